// Round 1
// baseline (2068.342 us; speedup 1.0000x reference)
//
#include <hip/hip_runtime.h>

#define DD 128   // feature dim
#define BR 64    // rows per GEMM block
#define KC 32    // k-chunk staged in LDS

// ---------------- GEMM 1: hp = relu(A @ W + b), dual-store to hp and neigh ----
__global__ __launch_bounds__(256) void k_gemm_pool(
    const float* __restrict__ A, const float* __restrict__ W,
    const float* __restrict__ bvec, float* __restrict__ hp,
    float* __restrict__ neigh, int nrows)
{
  __shared__ float Hs[BR][KC];
  __shared__ float Wss[KC][DD];
  const int tid = threadIdx.x;
  const int row0 = blockIdx.x * BR;
  const int ty = tid >> 4, tx = tid & 15;

  float acc[4][8];
#pragma unroll
  for (int i = 0; i < 4; i++)
#pragma unroll
    for (int j = 0; j < 8; j++) acc[i][j] = 0.f;

  for (int k0 = 0; k0 < DD; k0 += KC) {
#pragma unroll
    for (int q = 0; q < 2; q++) {
      int idx = tid + q * 256;
      int r = idx >> 3, c4 = (idx & 7) * 4;
      float4 v = make_float4(0.f, 0.f, 0.f, 0.f);
      if (row0 + r < nrows)
        v = *(const float4*)&A[(size_t)(row0 + r) * DD + k0 + c4];
      *(float4*)&Hs[r][c4] = v;
    }
#pragma unroll
    for (int q = 0; q < 4; q++) {
      int idx = tid + q * 256;
      int kk = idx >> 5, c4 = (idx & 31) * 4;
      *(float4*)&Wss[kk][c4] = *(const float4*)&W[(size_t)(k0 + kk) * DD + c4];
    }
    __syncthreads();
#pragma unroll
    for (int kk = 0; kk < KC; kk++) {
      float a[4];
      a[0] = Hs[ty*4+0][kk]; a[1] = Hs[ty*4+1][kk];
      a[2] = Hs[ty*4+2][kk]; a[3] = Hs[ty*4+3][kk];
      float4 w0 = *(const float4*)&Wss[kk][tx*8];
      float4 w1 = *(const float4*)&Wss[kk][tx*8+4];
      float w[8] = {w0.x,w0.y,w0.z,w0.w,w1.x,w1.y,w1.z,w1.w};
#pragma unroll
      for (int i = 0; i < 4; i++)
#pragma unroll
        for (int j = 0; j < 8; j++) acc[i][j] = fmaf(a[i], w[j], acc[i][j]);
    }
    __syncthreads();
  }
#pragma unroll
  for (int i = 0; i < 4; i++) {
    int r = row0 + ty*4 + i;
    if (r < nrows) {
      float o[8];
#pragma unroll
      for (int j = 0; j < 8; j++) o[j] = fmaxf(acc[i][j] + bvec[tx*8+j], 0.f);
      float4 v0 = make_float4(o[0],o[1],o[2],o[3]);
      float4 v1 = make_float4(o[4],o[5],o[6],o[7]);
      size_t base = (size_t)r * DD + tx*8;
      *(float4*)&hp[base]      = v0; *(float4*)&hp[base+4]    = v1;
      *(float4*)&neigh[base]   = v0; *(float4*)&neigh[base+4] = v1;
    }
  }
}

// ---------------- edge segment-max: one wave per edge ------------------------
__global__ __launch_bounds__(256) void k_edge_max(
    const int* __restrict__ src, const int* __restrict__ dst,
    const float* __restrict__ hp, float* __restrict__ neigh, int E)
{
  int e = blockIdx.x * 4 + (threadIdx.x >> 6);
  if (e >= E) return;
  int lane = threadIdx.x & 63;
  int s = src[e], d = dst[e];
  if (s == d) return;  // covered by neigh init = hp
  const float* hs = hp + (size_t)s * DD;
  unsigned int* nd = (unsigned int*)(neigh + (size_t)d * DD);
  float v0 = hs[lane];
  float v1 = hs[lane + 64];
  atomicMax(nd + lane,      __float_as_uint(v0));   // values >= 0: uint order == float order
  atomicMax(nd + lane + 64, __float_as_uint(v1));
}

// ---------------- GEMM 2: X = A@Ws + G@Wn + b, + BN stat accumulation --------
// NOTE: A may alias X (in-place across layers): each block reads only its own
// rows (all reads complete before epilogue stores). No __restrict__ on A/X.
__global__ __launch_bounds__(256) void k_gemm_out(
    const float* A, const float* __restrict__ G,
    const float* __restrict__ Ws, const float* __restrict__ Wn,
    const float* __restrict__ bvec, float* X,
    float* __restrict__ stats, int nrows)
{
  __shared__ float Hs[BR][KC];
  __shared__ float Wss[KC][DD];
  __shared__ float red[16][DD];
  const int tid = threadIdx.x;
  const int row0 = blockIdx.x * BR;
  const int ty = tid >> 4, tx = tid & 15;

  float acc[4][8];
#pragma unroll
  for (int i = 0; i < 4; i++)
#pragma unroll
    for (int j = 0; j < 8; j++) acc[i][j] = 0.f;

  for (int ch = 0; ch < 8; ch++) {
    const float* Asrc = (ch < 4) ? A : G;
    const float* Wsrc = (ch < 4) ? Ws : Wn;
    const int k0 = (ch & 3) * KC;
#pragma unroll
    for (int q = 0; q < 2; q++) {
      int idx = tid + q * 256;
      int r = idx >> 3, c4 = (idx & 7) * 4;
      float4 v = make_float4(0.f, 0.f, 0.f, 0.f);
      if (row0 + r < nrows)
        v = *(const float4*)&Asrc[(size_t)(row0 + r) * DD + k0 + c4];
      *(float4*)&Hs[r][c4] = v;
    }
#pragma unroll
    for (int q = 0; q < 4; q++) {
      int idx = tid + q * 256;
      int kk = idx >> 5, c4 = (idx & 31) * 4;
      *(float4*)&Wss[kk][c4] = *(const float4*)&Wsrc[(size_t)(k0 + kk) * DD + c4];
    }
    __syncthreads();
#pragma unroll
    for (int kk = 0; kk < KC; kk++) {
      float a[4];
      a[0] = Hs[ty*4+0][kk]; a[1] = Hs[ty*4+1][kk];
      a[2] = Hs[ty*4+2][kk]; a[3] = Hs[ty*4+3][kk];
      float4 w0 = *(const float4*)&Wss[kk][tx*8];
      float4 w1 = *(const float4*)&Wss[kk][tx*8+4];
      float w[8] = {w0.x,w0.y,w0.z,w0.w,w1.x,w1.y,w1.z,w1.w};
#pragma unroll
      for (int i = 0; i < 4; i++)
#pragma unroll
        for (int j = 0; j < 8; j++) acc[i][j] = fmaf(a[i], w[j], acc[i][j]);
    }
    __syncthreads();
  }

  // epilogue: add bias, store, zero invalid rows for stats
  float xs[4][8];
#pragma unroll
  for (int i = 0; i < 4; i++) {
    int r = row0 + ty*4 + i;
    bool ok = (r < nrows);
#pragma unroll
    for (int j = 0; j < 8; j++) {
      float v = acc[i][j] + bvec[tx*8+j];
      xs[i][j] = ok ? v : 0.f;
    }
    if (ok) {
      float4 v0 = make_float4(xs[i][0],xs[i][1],xs[i][2],xs[i][3]);
      float4 v1 = make_float4(xs[i][4],xs[i][5],xs[i][6],xs[i][7]);
      size_t base = (size_t)r * DD + tx*8;
      *(float4*)&X[base]   = v0;
      *(float4*)&X[base+4] = v1;
    }
  }

  // column sum
#pragma unroll
  for (int j = 0; j < 8; j++)
    red[ty][tx*8+j] = xs[0][j] + xs[1][j] + xs[2][j] + xs[3][j];
  __syncthreads();
  if (tid < DD) {
    float s = 0.f;
#pragma unroll
    for (int t = 0; t < 16; t++) s += red[t][tid];
    atomicAdd(&stats[tid], s);
  }
  __syncthreads();
  // column sum of squares
#pragma unroll
  for (int j = 0; j < 8; j++)
    red[ty][tx*8+j] = xs[0][j]*xs[0][j] + xs[1][j]*xs[1][j]
                    + xs[2][j]*xs[2][j] + xs[3][j]*xs[3][j];
  __syncthreads();
  if (tid < DD) {
    float s = 0.f;
#pragma unroll
    for (int t = 0; t < 16; t++) s += red[t][tid];
    atomicAdd(&stats[DD + tid], s);
  }
}

// ---------------- BN helpers -------------------------------------------------
__global__ void k_zero256(float* p) { p[threadIdx.x] = 0.f; }

__global__ void k_bn_prep(const float* __restrict__ stats,
                          const float* __restrict__ gamma,
                          const float* __restrict__ beta,
                          float* __restrict__ sc, float* __restrict__ sh,
                          float invN)
{
  int c = threadIdx.x;
  float mean = stats[c] * invN;
  float var  = stats[DD + c] * invN - mean * mean;
  float s = gamma[c] * rsqrtf(var + 1e-5f);
  sc[c] = s;
  sh[c] = beta[c] - mean * s;
}

__global__ __launch_bounds__(256) void k_bn_apply(
    float* X, const float* __restrict__ sc, const float* __restrict__ sh, int n4)
{
  int i = blockIdx.x * 256 + threadIdx.x;
  if (i >= n4) return;
  float4 v = ((float4*)X)[i];
  int c = (i * 4) & (DD - 1);
  v.x = fmaxf(fmaf(v.x, sc[c+0], sh[c+0]), 0.f);
  v.y = fmaxf(fmaf(v.y, sc[c+1], sh[c+1]), 0.f);
  v.z = fmaxf(fmaf(v.z, sc[c+2], sh[c+2]), 0.f);
  v.w = fmaxf(fmaf(v.w, sc[c+3], sh[c+3]), 0.f);
  ((float4*)X)[i] = v;
}

// ---------------- launcher ---------------------------------------------------
extern "C" void kernel_launch(void* const* d_in, const int* in_sizes, int n_in,
                              void* d_out, int out_size, void* d_ws, size_t ws_size,
                              hipStream_t stream)
{
  const float* feat    = (const float*)d_in[0];
  const float* W_pool  = (const float*)d_in[1];
  const float* b_pool  = (const float*)d_in[2];
  const float* W_self  = (const float*)d_in[3];
  const float* W_neigh = (const float*)d_in[4];
  const float* bias    = (const float*)d_in[5];
  const float* gamma   = (const float*)d_in[6];
  const float* beta    = (const float*)d_in[7];
  const int*   src     = (const int*)d_in[8];
  const int*   dst     = (const int*)d_in[9];

  const int Nn = in_sizes[0] / DD;   // 100000
  const int E  = in_sizes[8];        // 1600000
  float* out = (float*)d_out;

  float* hp    = (float*)d_ws;                 // N*D
  float* neigh = hp + (size_t)Nn * DD;         // N*D
  float* stats = neigh + (size_t)Nn * DD;      // 2*D (sum, sumsq)
  float* sc    = stats + 2 * DD;               // D
  float* sh    = sc + DD;                      // D

  const int gB = (Nn + BR - 1) / BR;           // 1563
  const int eB = (E + 3) / 4;                  // 400000
  const int n4 = Nn * (DD / 4);                // 3.2M
  const int aB = (n4 + 255) / 256;             // 12500

  const float* h = feat;
  for (int l = 0; l < 3; l++) {
    const float* Wp  = W_pool  + (size_t)l * DD * DD;
    const float* bp  = b_pool  + (size_t)l * DD;
    const float* Wsf = W_self  + (size_t)l * DD * DD;
    const float* Wn  = W_neigh + (size_t)l * DD * DD;
    const float* bl  = bias    + (size_t)l * DD;

    k_gemm_pool<<<gB, 256, 0, stream>>>(h, Wp, bp, hp, neigh, Nn);
    k_edge_max<<<eB, 256, 0, stream>>>(src, dst, hp, neigh, E);
    k_zero256<<<1, 256, 0, stream>>>(stats);
    k_gemm_out<<<gB, 256, 0, stream>>>(h, neigh, Wsf, Wn, bl, out, stats, Nn);
    k_bn_prep<<<1, DD, 0, stream>>>(stats, gamma + (size_t)l * DD,
                                    beta + (size_t)l * DD, sc, sh, 1.0f / (float)Nn);
    k_bn_apply<<<aB, 256, 0, stream>>>(out, sc, sh, n4);
    h = out;
  }
  (void)n_in; (void)out_size; (void)ws_size;
}

// Round 2
// 1097.569 us; speedup vs baseline: 1.8845x; 1.8845x over previous
//
#include <hip/hip_runtime.h>

#define DD 128   // feature dim
#define BR 64    // rows per GEMM block
#define KC 32    // k-chunk staged in LDS

// ---------------- GEMM 1: hp = relu(A @ W + b) -------------------------------
__global__ __launch_bounds__(256) void k_gemm_pool(
    const float* __restrict__ A, const float* __restrict__ W,
    const float* __restrict__ bvec, float* __restrict__ hp, int nrows)
{
  __shared__ float Hs[BR][KC];
  __shared__ float Wss[KC][DD];
  const int tid = threadIdx.x;
  const int row0 = blockIdx.x * BR;
  const int ty = tid >> 4, tx = tid & 15;

  float acc[4][8];
#pragma unroll
  for (int i = 0; i < 4; i++)
#pragma unroll
    for (int j = 0; j < 8; j++) acc[i][j] = 0.f;

  for (int k0 = 0; k0 < DD; k0 += KC) {
#pragma unroll
    for (int q = 0; q < 2; q++) {
      int idx = tid + q * 256;
      int r = idx >> 3, c4 = (idx & 7) * 4;
      float4 v = make_float4(0.f, 0.f, 0.f, 0.f);
      if (row0 + r < nrows)
        v = *(const float4*)&A[(size_t)(row0 + r) * DD + k0 + c4];
      *(float4*)&Hs[r][c4] = v;
    }
#pragma unroll
    for (int q = 0; q < 4; q++) {
      int idx = tid + q * 256;
      int kk = idx >> 5, c4 = (idx & 31) * 4;
      *(float4*)&Wss[kk][c4] = *(const float4*)&W[(size_t)(k0 + kk) * DD + c4];
    }
    __syncthreads();
#pragma unroll
    for (int kk = 0; kk < KC; kk++) {
      float a[4];
      a[0] = Hs[ty*4+0][kk]; a[1] = Hs[ty*4+1][kk];
      a[2] = Hs[ty*4+2][kk]; a[3] = Hs[ty*4+3][kk];
      float4 w0 = *(const float4*)&Wss[kk][tx*8];
      float4 w1 = *(const float4*)&Wss[kk][tx*8+4];
      float w[8] = {w0.x,w0.y,w0.z,w0.w,w1.x,w1.y,w1.z,w1.w};
#pragma unroll
      for (int i = 0; i < 4; i++)
#pragma unroll
        for (int j = 0; j < 8; j++) acc[i][j] = fmaf(a[i], w[j], acc[i][j]);
    }
    __syncthreads();
  }
#pragma unroll
  for (int i = 0; i < 4; i++) {
    int r = row0 + ty*4 + i;
    if (r < nrows) {
      float o[8];
#pragma unroll
      for (int j = 0; j < 8; j++) o[j] = fmaxf(acc[i][j] + bvec[tx*8+j], 0.f);
      size_t base = (size_t)r * DD + tx*8;
      *(float4*)&hp[base]   = make_float4(o[0],o[1],o[2],o[3]);
      *(float4*)&hp[base+4] = make_float4(o[4],o[5],o[6],o[7]);
    }
  }
}

// ---------------- CSR build (once per launch, reused for all 3 layers) -------
__global__ __launch_bounds__(256) void k_zero_i(int* p, int n) {
  int i = blockIdx.x * 256 + threadIdx.x;
  if (i < n) p[i] = 0;
}

__global__ __launch_bounds__(256) void k_hist(
    const int* __restrict__ dst, int* __restrict__ deg, int E)
{
  int e = blockIdx.x * 256 + threadIdx.x;
  if (e < E) atomicAdd(&deg[dst[e]], 1);
}

// per-block exclusive scan of deg -> off, block sums to bs
__global__ __launch_bounds__(256) void k_scan1(
    const int* __restrict__ deg, int* __restrict__ off, int* __restrict__ bs, int n)
{
  __shared__ int sm[256];
  int i = blockIdx.x * 256 + threadIdx.x;
  int v = (i < n) ? deg[i] : 0;
  sm[threadIdx.x] = v;
  __syncthreads();
  int acc = v;
#pragma unroll
  for (int s = 1; s < 256; s <<= 1) {
    int t = (threadIdx.x >= s) ? sm[threadIdx.x - s] : 0;
    __syncthreads();
    acc += t;
    sm[threadIdx.x] = acc;
    __syncthreads();
  }
  if (i < n) off[i] = acc - v;          // exclusive
  if (threadIdx.x == 255) bs[blockIdx.x] = acc;
}

__global__ void k_scan2(int* bs, int nb, int* off, int n, int E) {
  if (threadIdx.x == 0) {
    int run = 0;
    for (int i = 0; i < nb; i++) { int t = bs[i]; bs[i] = run; run += t; }
    off[n] = E;
  }
}

__global__ __launch_bounds__(256) void k_scan3(
    int* __restrict__ off, const int* __restrict__ bs, int n)
{
  int i = blockIdx.x * 256 + threadIdx.x;
  if (i < n) off[i] += bs[blockIdx.x];
}

__global__ __launch_bounds__(256) void k_scatter(
    const int* __restrict__ src, const int* __restrict__ dst,
    const int* __restrict__ off, int* __restrict__ cur,
    int* __restrict__ eidx, int E)
{
  int e = blockIdx.x * 256 + threadIdx.x;
  if (e >= E) return;
  int d = dst[e];
  int pos = off[d] + atomicAdd(&cur[d], 1);
  eidx[pos] = src[e];
}

// ---------------- aggregate: neigh[d] = max(hp[d], max_{s in in(d)} hp[s]) ---
__global__ __launch_bounds__(256) void k_aggregate(
    const float* __restrict__ hp, const int* __restrict__ off,
    const int* __restrict__ eidx, float* __restrict__ neigh, int nrows)
{
  int d = blockIdx.x * 4 + (threadIdx.x >> 6);
  if (d >= nrows) return;
  int lane = threadIdx.x & 63;
  size_t dbase = (size_t)d * DD + lane;
  float a0 = hp[dbase];
  float a1 = hp[dbase + 64];
  int b = off[d], e = off[d + 1];
  // 2-deep unroll for load/compute overlap
  int i = b;
  for (; i + 1 < e; i += 2) {
    int s0 = eidx[i], s1 = eidx[i + 1];
    const float* p0 = hp + (size_t)s0 * DD;
    const float* p1 = hp + (size_t)s1 * DD;
    float v00 = p0[lane], v01 = p0[lane + 64];
    float v10 = p1[lane], v11 = p1[lane + 64];
    a0 = fmaxf(a0, fmaxf(v00, v10));
    a1 = fmaxf(a1, fmaxf(v01, v11));
  }
  if (i < e) {
    const float* p = hp + (size_t)eidx[i] * DD;
    a0 = fmaxf(a0, p[lane]);
    a1 = fmaxf(a1, p[lane + 64]);
  }
  neigh[dbase] = a0;
  neigh[dbase + 64] = a1;
}

// ---------------- GEMM 2: X = A@Ws + G@Wn + b, + BN stat accumulation --------
// NOTE: A may alias X (in-place across layers): each block reads only its own
// rows (all reads complete before epilogue stores). No __restrict__ on A/X.
__global__ __launch_bounds__(256) void k_gemm_out(
    const float* A, const float* __restrict__ G,
    const float* __restrict__ Ws, const float* __restrict__ Wn,
    const float* __restrict__ bvec, float* X,
    float* __restrict__ stats, int nrows)
{
  __shared__ float Hs[BR][KC];
  __shared__ float Wss[KC][DD];
  __shared__ float red[16][DD];
  const int tid = threadIdx.x;
  const int row0 = blockIdx.x * BR;
  const int ty = tid >> 4, tx = tid & 15;

  float acc[4][8];
#pragma unroll
  for (int i = 0; i < 4; i++)
#pragma unroll
    for (int j = 0; j < 8; j++) acc[i][j] = 0.f;

  for (int ch = 0; ch < 8; ch++) {
    const float* Asrc = (ch < 4) ? A : G;
    const float* Wsrc = (ch < 4) ? Ws : Wn;
    const int k0 = (ch & 3) * KC;
#pragma unroll
    for (int q = 0; q < 2; q++) {
      int idx = tid + q * 256;
      int r = idx >> 3, c4 = (idx & 7) * 4;
      float4 v = make_float4(0.f, 0.f, 0.f, 0.f);
      if (row0 + r < nrows)
        v = *(const float4*)&Asrc[(size_t)(row0 + r) * DD + k0 + c4];
      *(float4*)&Hs[r][c4] = v;
    }
#pragma unroll
    for (int q = 0; q < 4; q++) {
      int idx = tid + q * 256;
      int kk = idx >> 5, c4 = (idx & 31) * 4;
      *(float4*)&Wss[kk][c4] = *(const float4*)&Wsrc[(size_t)(k0 + kk) * DD + c4];
    }
    __syncthreads();
#pragma unroll
    for (int kk = 0; kk < KC; kk++) {
      float a[4];
      a[0] = Hs[ty*4+0][kk]; a[1] = Hs[ty*4+1][kk];
      a[2] = Hs[ty*4+2][kk]; a[3] = Hs[ty*4+3][kk];
      float4 w0 = *(const float4*)&Wss[kk][tx*8];
      float4 w1 = *(const float4*)&Wss[kk][tx*8+4];
      float w[8] = {w0.x,w0.y,w0.z,w0.w,w1.x,w1.y,w1.z,w1.w};
#pragma unroll
      for (int i = 0; i < 4; i++)
#pragma unroll
        for (int j = 0; j < 8; j++) acc[i][j] = fmaf(a[i], w[j], acc[i][j]);
    }
    __syncthreads();
  }

  // epilogue: add bias, store, zero invalid rows for stats
  float xs[4][8];
#pragma unroll
  for (int i = 0; i < 4; i++) {
    int r = row0 + ty*4 + i;
    bool ok = (r < nrows);
#pragma unroll
    for (int j = 0; j < 8; j++) {
      float v = acc[i][j] + bvec[tx*8+j];
      xs[i][j] = ok ? v : 0.f;
    }
    if (ok) {
      size_t base = (size_t)r * DD + tx*8;
      *(float4*)&X[base]   = make_float4(xs[i][0],xs[i][1],xs[i][2],xs[i][3]);
      *(float4*)&X[base+4] = make_float4(xs[i][4],xs[i][5],xs[i][6],xs[i][7]);
    }
  }

  // column sum
#pragma unroll
  for (int j = 0; j < 8; j++)
    red[ty][tx*8+j] = xs[0][j] + xs[1][j] + xs[2][j] + xs[3][j];
  __syncthreads();
  if (tid < DD) {
    float s = 0.f;
#pragma unroll
    for (int t = 0; t < 16; t++) s += red[t][tid];
    atomicAdd(&stats[tid], s);
  }
  __syncthreads();
  // column sum of squares
#pragma unroll
  for (int j = 0; j < 8; j++)
    red[ty][tx*8+j] = xs[0][j]*xs[0][j] + xs[1][j]*xs[1][j]
                    + xs[2][j]*xs[2][j] + xs[3][j]*xs[3][j];
  __syncthreads();
  if (tid < DD) {
    float s = 0.f;
#pragma unroll
    for (int t = 0; t < 16; t++) s += red[t][tid];
    atomicAdd(&stats[DD + tid], s);
  }
}

// ---------------- BN helpers -------------------------------------------------
__global__ void k_zero256(float* p) { p[threadIdx.x] = 0.f; }

__global__ void k_bn_prep(const float* __restrict__ stats,
                          const float* __restrict__ gamma,
                          const float* __restrict__ beta,
                          float* __restrict__ sc, float* __restrict__ sh,
                          float invN)
{
  int c = threadIdx.x;
  float mean = stats[c] * invN;
  float var  = stats[DD + c] * invN - mean * mean;
  float s = gamma[c] * rsqrtf(var + 1e-5f);
  sc[c] = s;
  sh[c] = beta[c] - mean * s;
}

__global__ __launch_bounds__(256) void k_bn_apply(
    float* X, const float* __restrict__ sc, const float* __restrict__ sh, int n4)
{
  int i = blockIdx.x * 256 + threadIdx.x;
  if (i >= n4) return;
  float4 v = ((float4*)X)[i];
  int c = (i * 4) & (DD - 1);
  v.x = fmaxf(fmaf(v.x, sc[c+0], sh[c+0]), 0.f);
  v.y = fmaxf(fmaf(v.y, sc[c+1], sh[c+1]), 0.f);
  v.z = fmaxf(fmaf(v.z, sc[c+2], sh[c+2]), 0.f);
  v.w = fmaxf(fmaf(v.w, sc[c+3], sh[c+3]), 0.f);
  ((float4*)X)[i] = v;
}

// ---------------- launcher ---------------------------------------------------
extern "C" void kernel_launch(void* const* d_in, const int* in_sizes, int n_in,
                              void* d_out, int out_size, void* d_ws, size_t ws_size,
                              hipStream_t stream)
{
  const float* feat    = (const float*)d_in[0];
  const float* W_pool  = (const float*)d_in[1];
  const float* b_pool  = (const float*)d_in[2];
  const float* W_self  = (const float*)d_in[3];
  const float* W_neigh = (const float*)d_in[4];
  const float* bias    = (const float*)d_in[5];
  const float* gamma   = (const float*)d_in[6];
  const float* beta    = (const float*)d_in[7];
  const int*   src     = (const int*)d_in[8];
  const int*   dst     = (const int*)d_in[9];

  const int Nn = in_sizes[0] / DD;   // 100000
  const int E  = in_sizes[8];        // 1600000
  float* out = (float*)d_out;

  // workspace layout
  float* hp    = (float*)d_ws;                   // N*D floats
  float* neigh = hp + (size_t)Nn * DD;           // N*D floats
  float* stats = neigh + (size_t)Nn * DD;        // 2*D
  float* sc    = stats + 2 * DD;                 // D
  float* sh    = sc + DD;                        // D
  int*   deg   = (int*)(sh + DD);                // N (also scatter cursor)
  int*   off   = deg + Nn;                       // N+1
  int*   bs    = off + Nn + 1;                   // nscan blocks
  const int nsb = (Nn + 255) / 256;              // 391
  int*   eidx  = bs + nsb;                       // E

  const int gB = (Nn + BR - 1) / BR;
  const int eB = (E + 255) / 256;
  const int aggB = (Nn + 3) / 4;
  const int n4 = Nn * (DD / 4);
  const int aB = (n4 + 255) / 256;

  // ---- build CSR (dst-sorted) once ----
  k_zero_i<<<nsb, 256, 0, stream>>>(deg, Nn);
  k_hist<<<eB, 256, 0, stream>>>(dst, deg, E);
  k_scan1<<<nsb, 256, 0, stream>>>(deg, off, bs, Nn);
  k_scan2<<<1, 64, 0, stream>>>(bs, nsb, off, Nn, E);
  k_scan3<<<nsb, 256, 0, stream>>>(off, bs, Nn);
  k_zero_i<<<nsb, 256, 0, stream>>>(deg, Nn);    // reuse deg as cursor
  k_scatter<<<eB, 256, 0, stream>>>(src, dst, off, deg, eidx, E);

  const float* h = feat;
  for (int l = 0; l < 3; l++) {
    const float* Wp  = W_pool  + (size_t)l * DD * DD;
    const float* bp  = b_pool  + (size_t)l * DD;
    const float* Wsf = W_self  + (size_t)l * DD * DD;
    const float* Wn  = W_neigh + (size_t)l * DD * DD;
    const float* bl  = bias    + (size_t)l * DD;

    k_gemm_pool<<<gB, 256, 0, stream>>>(h, Wp, bp, hp, Nn);
    k_aggregate<<<aggB, 256, 0, stream>>>(hp, off, eidx, neigh, Nn);
    k_zero256<<<1, 256, 0, stream>>>(stats);
    k_gemm_out<<<gB, 256, 0, stream>>>(h, neigh, Wsf, Wn, bl, out, stats, Nn);
    k_bn_prep<<<1, DD, 0, stream>>>(stats, gamma + (size_t)l * DD,
                                    beta + (size_t)l * DD, sc, sh, 1.0f / (float)Nn);
    k_bn_apply<<<aB, 256, 0, stream>>>(out, sc, sh, n4);
    h = out;
  }
  (void)n_in; (void)out_size; (void)ws_size;
}

// Round 3
// 855.017 us; speedup vs baseline: 2.4191x; 1.2837x over previous
//
#include <hip/hip_runtime.h>

#define DD 128
#define SB 256   // stats partial blocks

typedef unsigned short u16;
typedef unsigned int   u32;
typedef __attribute__((ext_vector_type(8))) short bf16x8;
typedef __attribute__((ext_vector_type(4))) float f32x4;

__device__ inline u16 f2bf(float x) {
  u32 u = __float_as_uint(x);
  u += 0x7fffu + ((u >> 16) & 1u);
  return (u16)(u >> 16);
}
__device__ inline float bf2f_lo(u32 w) { return __uint_as_float(w << 16); }
__device__ inline float bf2f_hi(u32 w) { return __uint_as_float(w & 0xffff0000u); }
__device__ inline u32 bmax(u32 a, u32 b) {
  u32 al = a & 0xffffu, bl = b & 0xffffu;
  u32 ah = a >> 16,     bh = b >> 16;
  u32 lo = al > bl ? al : bl;
  u32 hi = ah > bh ? ah : bh;
  return lo | (hi << 16);
}

// ---- pack 9 weight matrices (fp32 [k][n]) into MFMA A-frag layout, bf16 ----
// Wpk[m][((ks*8+nt)*64+l)*8+j] = W[ks*32+(l>>4)*8+j][nt*16+(l&15)]
__global__ __launch_bounds__(256) void k_pack_w(
    const float* __restrict__ Wp, const float* __restrict__ Wsf,
    const float* __restrict__ Wn, u16* __restrict__ Wpk)
{
  int g = blockIdx.x * 256 + threadIdx.x;      // 9 * 2048
  int m = g >> 11;
  if (m >= 9) return;
  int t = g & 2047;
  const float* W = (m < 3) ? Wp + (size_t)m * 16384
                 : (m < 6) ? Wsf + (size_t)(m - 3) * 16384
                           : Wn + (size_t)(m - 6) * 16384;
  int ks = t >> 9, nt = (t >> 6) & 7, l = t & 63;
  int kbase = ks * 32 + (l >> 4) * 8;
  int n = nt * 16 + (l & 15);
  u32 o[4];
#pragma unroll
  for (int p = 0; p < 4; p++) {
    u16 e0 = f2bf(W[(size_t)(kbase + 2 * p) * DD + n]);
    u16 e1 = f2bf(W[(size_t)(kbase + 2 * p + 1) * DD + n]);
    o[p] = (u32)e0 | ((u32)e1 << 16);
  }
  uint4* dst = (uint4*)(Wpk + (size_t)m * 16384 + (size_t)t * 8);
  *dst = make_uint4(o[0], o[1], o[2], o[3]);
}

// ---- fp32 -> bf16 cast (feat -> hb) ----------------------------------------
__global__ __launch_bounds__(256) void k_cast(
    const float* __restrict__ x, u16* __restrict__ y, int n8)
{
  int i = blockIdx.x * 256 + threadIdx.x;
  if (i >= n8) return;
  float4 a = ((const float4*)x)[2 * i];
  float4 b = ((const float4*)x)[2 * i + 1];
  uint4 o;
  o.x = (u32)f2bf(a.x) | ((u32)f2bf(a.y) << 16);
  o.y = (u32)f2bf(a.z) | ((u32)f2bf(a.w) << 16);
  o.z = (u32)f2bf(b.x) | ((u32)f2bf(b.y) << 16);
  o.w = (u32)f2bf(b.z) | ((u32)f2bf(b.w) << 16);
  ((uint4*)y)[i] = o;
}

// ---- GEMM 1: hp = relu(hb @ W + b), bf16 MFMA, no LDS ----------------------
__global__ __launch_bounds__(256, 2) void k_gemm_pool(
    const u16* __restrict__ hb, const u16* __restrict__ Wpk,
    const float* __restrict__ bvec, u16* __restrict__ hp, int nrows)
{
  const int tid = threadIdx.x;
  const int w = tid >> 6, l = tid & 63;
  const int lg = l >> 4, lm = l & 15;
  const int m0 = blockIdx.x * 128 + w * 32;

  f32x4 acc[2][8];
#pragma unroll
  for (int a = 0; a < 2; a++)
#pragma unroll
    for (int b = 0; b < 8; b++) acc[a][b] = (f32x4){0.f, 0.f, 0.f, 0.f};

  int n0 = m0 + lm;      if (n0 >= nrows) n0 = nrows - 1;
  int n1 = m0 + 16 + lm; if (n1 >= nrows) n1 = nrows - 1;
  const u16* hr0 = hb + (size_t)n0 * DD + lg * 8;
  const u16* hr1 = hb + (size_t)n1 * DD + lg * 8;
  const u16* wl = Wpk + l * 8;

#pragma unroll
  for (int ks = 0; ks < 4; ks++) {
    bf16x8 h0 = *(const bf16x8*)(hr0 + ks * 32);
    bf16x8 h1 = *(const bf16x8*)(hr1 + ks * 32);
#pragma unroll
    for (int nt = 0; nt < 8; nt++) {
      bf16x8 wf = *(const bf16x8*)(wl + (ks * 8 + nt) * 512);
      acc[0][nt] = __builtin_amdgcn_mfma_f32_16x16x32_bf16(wf, h0, acc[0][nt], 0, 0, 0);
      acc[1][nt] = __builtin_amdgcn_mfma_f32_16x16x32_bf16(wf, h1, acc[1][nt], 0, 0, 0);
    }
  }

#pragma unroll
  for (int mf = 0; mf < 2; mf++) {
    int node = m0 + mf * 16 + lm;
    if (node < nrows) {
      u16* dst = hp + (size_t)node * DD + lg * 4;
#pragma unroll
      for (int nt = 0; nt < 8; nt++) {
        float4 b4 = *(const float4*)(bvec + nt * 16 + lg * 4);
        f32x4 a = acc[mf][nt];
        float v0 = fmaxf(a[0] + b4.x, 0.f);
        float v1 = fmaxf(a[1] + b4.y, 0.f);
        float v2 = fmaxf(a[2] + b4.z, 0.f);
        float v3 = fmaxf(a[3] + b4.w, 0.f);
        uint2 o;
        o.x = (u32)f2bf(v0) | ((u32)f2bf(v1) << 16);
        o.y = (u32)f2bf(v2) | ((u32)f2bf(v3) << 16);
        *(uint2*)(dst + nt * 16) = o;
      }
    }
  }
}

// ---- GEMM 2: xb = hb@Ws + neigh@Wn + b (bf16 out, no relu) -----------------
__global__ __launch_bounds__(256, 2) void k_gemm_out(
    const u16* __restrict__ hb, const u16* __restrict__ gb,
    const u16* __restrict__ WpkS, const u16* __restrict__ WpkN,
    const float* __restrict__ bvec, u16* __restrict__ xb, int nrows)
{
  const int tid = threadIdx.x;
  const int w = tid >> 6, l = tid & 63;
  const int lg = l >> 4, lm = l & 15;
  const int m0 = blockIdx.x * 128 + w * 32;

  f32x4 acc[2][8];
#pragma unroll
  for (int a = 0; a < 2; a++)
#pragma unroll
    for (int b = 0; b < 8; b++) acc[a][b] = (f32x4){0.f, 0.f, 0.f, 0.f};

  int n0 = m0 + lm;      if (n0 >= nrows) n0 = nrows - 1;
  int n1 = m0 + 16 + lm; if (n1 >= nrows) n1 = nrows - 1;

#pragma unroll
  for (int pass = 0; pass < 2; pass++) {
    const u16* B = pass ? gb : hb;
    const u16* wl = (pass ? WpkN : WpkS) + l * 8;
    const u16* hr0 = B + (size_t)n0 * DD + lg * 8;
    const u16* hr1 = B + (size_t)n1 * DD + lg * 8;
#pragma unroll
    for (int ks = 0; ks < 4; ks++) {
      bf16x8 h0 = *(const bf16x8*)(hr0 + ks * 32);
      bf16x8 h1 = *(const bf16x8*)(hr1 + ks * 32);
#pragma unroll
      for (int nt = 0; nt < 8; nt++) {
        bf16x8 wf = *(const bf16x8*)(wl + (ks * 8 + nt) * 512);
        acc[0][nt] = __builtin_amdgcn_mfma_f32_16x16x32_bf16(wf, h0, acc[0][nt], 0, 0, 0);
        acc[1][nt] = __builtin_amdgcn_mfma_f32_16x16x32_bf16(wf, h1, acc[1][nt], 0, 0, 0);
      }
    }
  }

#pragma unroll
  for (int mf = 0; mf < 2; mf++) {
    int node = m0 + mf * 16 + lm;
    if (node < nrows) {
      u16* dst = xb + (size_t)node * DD + lg * 4;
#pragma unroll
      for (int nt = 0; nt < 8; nt++) {
        float4 b4 = *(const float4*)(bvec + nt * 16 + lg * 4);
        f32x4 a = acc[mf][nt];
        uint2 o;
        o.x = (u32)f2bf(a[0] + b4.x) | ((u32)f2bf(a[1] + b4.y) << 16);
        o.y = (u32)f2bf(a[2] + b4.z) | ((u32)f2bf(a[3] + b4.w) << 16);
        *(uint2*)(dst + nt * 16) = o;
      }
    }
  }
}

// ---- CSR build --------------------------------------------------------------
__global__ __launch_bounds__(256) void k_zero_i(int* p, int n) {
  int i = blockIdx.x * 256 + threadIdx.x;
  if (i < n) p[i] = 0;
}

__global__ __launch_bounds__(256) void k_hist(
    const int* __restrict__ dst, int* __restrict__ deg, int E)
{
  int e = blockIdx.x * 256 + threadIdx.x;
  if (e < E) atomicAdd(&deg[dst[e]], 1);
}

__global__ __launch_bounds__(256) void k_scan1(
    const int* __restrict__ deg, int* __restrict__ off, int* __restrict__ bs, int n)
{
  __shared__ int sm[256];
  int i = blockIdx.x * 256 + threadIdx.x;
  int v = (i < n) ? deg[i] : 0;
  sm[threadIdx.x] = v;
  __syncthreads();
  int acc = v;
#pragma unroll
  for (int s = 1; s < 256; s <<= 1) {
    int t = (threadIdx.x >= s) ? sm[threadIdx.x - s] : 0;
    __syncthreads();
    acc += t;
    sm[threadIdx.x] = acc;
    __syncthreads();
  }
  if (i < n) off[i] = acc - v;
  if (threadIdx.x == 255) bs[blockIdx.x] = acc;
}

__global__ void k_scan2(int* bs, int nb, int* off, int n, int E) {
  if (threadIdx.x == 0) {
    int run = 0;
    for (int i = 0; i < nb; i++) { int t = bs[i]; bs[i] = run; run += t; }
    off[n] = E;
  }
}

__global__ __launch_bounds__(256) void k_scan3(
    int* __restrict__ off, const int* __restrict__ bs, int n)
{
  int i = blockIdx.x * 256 + threadIdx.x;
  if (i < n) off[i] += bs[blockIdx.x];
}

__global__ __launch_bounds__(256) void k_scatter(
    const int* __restrict__ src, const int* __restrict__ dst,
    const int* __restrict__ off, int* __restrict__ cur,
    int* __restrict__ eidx, int E)
{
  int e = blockIdx.x * 256 + threadIdx.x;
  if (e >= E) return;
  int d = dst[e];
  int pos = off[d] + atomicAdd(&cur[d], 1);
  eidx[pos] = src[e];
}

// ---- aggregate: neigh[d] = max(hp[d], max over in-edges), bf16 -------------
__global__ __launch_bounds__(256) void k_aggregate(
    const u32* __restrict__ hp, const int* __restrict__ off,
    const int* __restrict__ eidx, u32* __restrict__ nb, int nrows)
{
  int d = blockIdx.x * 4 + (threadIdx.x >> 6);
  if (d >= nrows) return;
  int lane = threadIdx.x & 63;
  u32 a = hp[(size_t)d * 64 + lane];
  int b = off[d], e = off[d + 1];
  int i = b;
  for (; i + 3 < e; i += 4) {
    int s0 = eidx[i], s1 = eidx[i + 1], s2 = eidx[i + 2], s3 = eidx[i + 3];
    u32 v0 = hp[(size_t)s0 * 64 + lane];
    u32 v1 = hp[(size_t)s1 * 64 + lane];
    u32 v2 = hp[(size_t)s2 * 64 + lane];
    u32 v3 = hp[(size_t)s3 * 64 + lane];
    a = bmax(a, bmax(bmax(v0, v1), bmax(v2, v3)));
  }
  for (; i < e; i++) a = bmax(a, hp[(size_t)eidx[i] * 64 + lane]);
  nb[(size_t)d * 64 + lane] = a;
}

// ---- BN stats: per-block partial column sums/sumsq over bf16 X -------------
__global__ __launch_bounds__(256) void k_stats(
    const u16* __restrict__ xb, float* __restrict__ parts, int nchunks)
{
  __shared__ float sm[256][8];
  int t = threadIdx.x;
  float s[8], q[8];
#pragma unroll
  for (int j = 0; j < 8; j++) { s[j] = 0.f; q[j] = 0.f; }
  for (int i = blockIdx.x * 256 + t; i < nchunks; i += gridDim.x * 256) {
    uint4 v = ((const uint4*)xb)[i];
    u32 wv0 = v.x, wv1 = v.y, wv2 = v.z, wv3 = v.w;
    float f;
    f = bf2f_lo(wv0); s[0] += f; q[0] += f * f;
    f = bf2f_hi(wv0); s[1] += f; q[1] += f * f;
    f = bf2f_lo(wv1); s[2] += f; q[2] += f * f;
    f = bf2f_hi(wv1); s[3] += f; q[3] += f * f;
    f = bf2f_lo(wv2); s[4] += f; q[4] += f * f;
    f = bf2f_hi(wv2); s[5] += f; q[5] += f * f;
    f = bf2f_lo(wv3); s[6] += f; q[6] += f * f;
    f = bf2f_hi(wv3); s[7] += f; q[7] += f * f;
  }
#pragma unroll
  for (int j = 0; j < 8; j++) sm[t][j] = s[j];
  __syncthreads();
  if (t < 128) {
    int fc = t >> 3, j = t & 7;
    float a = 0.f;
#pragma unroll
    for (int g = 0; g < 16; g++) a += sm[g * 16 + fc][j];
    parts[blockIdx.x * 256 + t] = a;
  }
  __syncthreads();
#pragma unroll
  for (int j = 0; j < 8; j++) sm[t][j] = q[j];
  __syncthreads();
  if (t < 128) {
    int fc = t >> 3, j = t & 7;
    float a = 0.f;
#pragma unroll
    for (int g = 0; g < 16; g++) a += sm[g * 16 + fc][j];
    parts[blockIdx.x * 256 + 128 + t] = a;
  }
}

__global__ void k_bn_prep(const float* __restrict__ parts, int nb,
                          const float* __restrict__ gamma,
                          const float* __restrict__ beta,
                          float* __restrict__ sc, float* __restrict__ sh,
                          float invN)
{
  int f = threadIdx.x;  // 128
  float s = 0.f, q = 0.f;
  for (int b = 0; b < nb; b++) {
    s += parts[b * 256 + f];
    q += parts[b * 256 + 128 + f];
  }
  float mean = s * invN;
  float var = q * invN - mean * mean;
  float g = gamma[f] * rsqrtf(var + 1e-5f);
  sc[f] = g;
  sh[f] = beta[f] - mean * g;
}

__global__ __launch_bounds__(256) void k_bn_apply(
    const u16* __restrict__ xb, u16* __restrict__ hb, float* __restrict__ out,
    const float* __restrict__ sc, const float* __restrict__ sh, int n8, int last)
{
  int i = blockIdx.x * 256 + threadIdx.x;
  if (i >= n8) return;
  uint4 v = ((const uint4*)xb)[i];
  int f0 = (i & 15) * 8;
  float4 c0 = *(const float4*)(sc + f0);
  float4 c1 = *(const float4*)(sc + f0 + 4);
  float4 h0 = *(const float4*)(sh + f0);
  float4 h1 = *(const float4*)(sh + f0 + 4);
  float y0 = fmaxf(fmaf(bf2f_lo(v.x), c0.x, h0.x), 0.f);
  float y1 = fmaxf(fmaf(bf2f_hi(v.x), c0.y, h0.y), 0.f);
  float y2 = fmaxf(fmaf(bf2f_lo(v.y), c0.z, h0.z), 0.f);
  float y3 = fmaxf(fmaf(bf2f_hi(v.y), c0.w, h0.w), 0.f);
  float y4 = fmaxf(fmaf(bf2f_lo(v.z), c1.x, h1.x), 0.f);
  float y5 = fmaxf(fmaf(bf2f_hi(v.z), c1.y, h1.y), 0.f);
  float y6 = fmaxf(fmaf(bf2f_lo(v.w), c1.z, h1.z), 0.f);
  float y7 = fmaxf(fmaf(bf2f_hi(v.w), c1.w, h1.w), 0.f);
  if (last) {
    float4* o = (float4*)out + 2 * (size_t)i;
    o[0] = make_float4(y0, y1, y2, y3);
    o[1] = make_float4(y4, y5, y6, y7);
  } else {
    uint4 o;
    o.x = (u32)f2bf(y0) | ((u32)f2bf(y1) << 16);
    o.y = (u32)f2bf(y2) | ((u32)f2bf(y3) << 16);
    o.z = (u32)f2bf(y4) | ((u32)f2bf(y5) << 16);
    o.w = (u32)f2bf(y6) | ((u32)f2bf(y7) << 16);
    ((uint4*)hb)[i] = o;
  }
}

// ---- launcher ---------------------------------------------------------------
extern "C" void kernel_launch(void* const* d_in, const int* in_sizes, int n_in,
                              void* d_out, int out_size, void* d_ws, size_t ws_size,
                              hipStream_t stream)
{
  const float* feat    = (const float*)d_in[0];
  const float* W_pool  = (const float*)d_in[1];
  const float* b_pool  = (const float*)d_in[2];
  const float* W_self  = (const float*)d_in[3];
  const float* W_neigh = (const float*)d_in[4];
  const float* bias    = (const float*)d_in[5];
  const float* gamma   = (const float*)d_in[6];
  const float* beta    = (const float*)d_in[7];
  const int*   src     = (const int*)d_in[8];
  const int*   dst     = (const int*)d_in[9];

  const int Nn = in_sizes[0] / DD;   // 100000
  const int E  = in_sizes[8];        // 1600000
  float* out = (float*)d_out;

  const size_t ND = (size_t)Nn * DD;
  u16*   hb    = (u16*)d_ws;                    // ND bf16
  u16*   hp    = hb + ND;                       // ND bf16 (also xb)
  u16*   nbuf  = hp + ND;                       // ND bf16
  u16*   Wpk   = nbuf + ND;                     // 9*16384 bf16
  float* parts = (float*)(Wpk + 9 * 16384);     // SB*256 f32
  float* sc    = parts + SB * 256;              // 128
  float* sh    = sc + DD;                       // 128
  int*   deg   = (int*)(sh + DD);               // N
  int*   off   = deg + Nn;                      // N+1
  const int nsb = (Nn + 255) / 256;
  int*   bs    = off + Nn + 1;                  // nsb
  int*   eidx  = bs + nsb;                      // E

  const int gB   = (Nn + 127) / 128;            // 782
  const int eB   = (E + 255) / 256;
  const int aggB = (Nn + 3) / 4;
  const int n8   = Nn * (DD / 8);               // 1.6M
  const int cB   = (n8 + 255) / 256;

  // one-time setup
  k_pack_w<<<72, 256, 0, stream>>>(W_pool, W_self, W_neigh, Wpk);
  k_cast<<<cB, 256, 0, stream>>>(feat, hb, n8);
  k_zero_i<<<nsb, 256, 0, stream>>>(deg, Nn);
  k_hist<<<eB, 256, 0, stream>>>(dst, deg, E);
  k_scan1<<<nsb, 256, 0, stream>>>(deg, off, bs, Nn);
  k_scan2<<<1, 64, 0, stream>>>(bs, nsb, off, Nn, E);
  k_scan3<<<nsb, 256, 0, stream>>>(off, bs, Nn);
  k_zero_i<<<nsb, 256, 0, stream>>>(deg, Nn);
  k_scatter<<<eB, 256, 0, stream>>>(src, dst, off, deg, eidx, E);

  for (int l = 0; l < 3; l++) {
    const float* bp = b_pool + (size_t)l * DD;
    const float* bl = bias + (size_t)l * DD;
    k_gemm_pool<<<gB, 256, 0, stream>>>(hb, Wpk + (size_t)l * 16384, bp, hp, Nn);
    k_aggregate<<<aggB, 256, 0, stream>>>((const u32*)hp, off, eidx, (u32*)nbuf, Nn);
    k_gemm_out<<<gB, 256, 0, stream>>>(hb, nbuf, Wpk + (size_t)(3 + l) * 16384,
                                       Wpk + (size_t)(6 + l) * 16384, bl, hp, Nn);
    k_stats<<<SB, 256, 0, stream>>>(hp, parts, Nn * 16);
    k_bn_prep<<<1, 128, 0, stream>>>(parts, SB, gamma + (size_t)l * DD,
                                     beta + (size_t)l * DD, sc, sh, 1.0f / (float)Nn);
    k_bn_apply<<<cB, 256, 0, stream>>>(hp, hb, out, sc, sh, n8, l == 2);
  }
  (void)n_in; (void)out_size; (void)ws_size;
}

// Round 4
// 845.237 us; speedup vs baseline: 2.4471x; 1.0116x over previous
//
#include <hip/hip_runtime.h>

#define DD 128
#define SB 128    // stats partial blocks
#define MAXB 256  // max dst-buckets (supports N <= 131072)
#define BSH 9     // bucket = dst >> 9  (512 nodes/bucket)

typedef unsigned short u16;
typedef unsigned int   u32;
typedef __attribute__((ext_vector_type(8))) short bf16x8;
typedef __attribute__((ext_vector_type(4))) float f32x4;

__device__ inline u16 f2bf(float x) {
  u32 u = __float_as_uint(x);
  u += 0x7fffu + ((u >> 16) & 1u);
  return (u16)(u >> 16);
}
__device__ inline float bf2f_lo(u32 w) { return __uint_as_float(w << 16); }
__device__ inline float bf2f_hi(u32 w) { return __uint_as_float(w & 0xffff0000u); }
__device__ inline u32 bmax(u32 a, u32 b) {
  u32 al = a & 0xffffu, bl = b & 0xffffu;
  u32 ah = a >> 16,     bh = b >> 16;
  u32 lo = al > bl ? al : bl;
  u32 hi = ah > bh ? ah : bh;
  return lo | (hi << 16);
}

// ---- pack 9 weight matrices (fp32 [k][n]) into MFMA A-frag layout, bf16 ----
__global__ __launch_bounds__(256) void k_pack_w(
    const float* __restrict__ Wp, const float* __restrict__ Wsf,
    const float* __restrict__ Wn, u16* __restrict__ Wpk)
{
  int g = blockIdx.x * 256 + threadIdx.x;      // 9 * 2048
  int m = g >> 11;
  if (m >= 9) return;
  int t = g & 2047;
  const float* W = (m < 3) ? Wp + (size_t)m * 16384
                 : (m < 6) ? Wsf + (size_t)(m - 3) * 16384
                           : Wn + (size_t)(m - 6) * 16384;
  int ks = t >> 9, nt = (t >> 6) & 7, l = t & 63;
  int kbase = ks * 32 + (l >> 4) * 8;
  int n = nt * 16 + (l & 15);
  u32 o[4];
#pragma unroll
  for (int p = 0; p < 4; p++) {
    u16 e0 = f2bf(W[(size_t)(kbase + 2 * p) * DD + n]);
    u16 e1 = f2bf(W[(size_t)(kbase + 2 * p + 1) * DD + n]);
    o[p] = (u32)e0 | ((u32)e1 << 16);
  }
  uint4* dst = (uint4*)(Wpk + (size_t)m * 16384 + (size_t)t * 8);
  *dst = make_uint4(o[0], o[1], o[2], o[3]);
}

// ---- fp32 -> bf16 cast ------------------------------------------------------
__global__ __launch_bounds__(256) void k_cast(
    const float* __restrict__ x, u16* __restrict__ y, int n8)
{
  int i = blockIdx.x * 256 + threadIdx.x;
  if (i >= n8) return;
  float4 a = ((const float4*)x)[2 * i];
  float4 b = ((const float4*)x)[2 * i + 1];
  uint4 o;
  o.x = (u32)f2bf(a.x) | ((u32)f2bf(a.y) << 16);
  o.y = (u32)f2bf(a.z) | ((u32)f2bf(a.w) << 16);
  o.z = (u32)f2bf(b.x) | ((u32)f2bf(b.y) << 16);
  o.w = (u32)f2bf(b.z) | ((u32)f2bf(b.w) << 16);
  ((uint4*)y)[i] = o;
}

// ---- GEMM 1: hp = relu(hb @ W + b), bf16 MFMA, no LDS ----------------------
__global__ __launch_bounds__(256, 2) void k_gemm_pool(
    const u16* __restrict__ hb, const u16* __restrict__ Wpk,
    const float* __restrict__ bvec, u16* __restrict__ hp, int nrows)
{
  const int tid = threadIdx.x;
  const int w = tid >> 6, l = tid & 63;
  const int lg = l >> 4, lm = l & 15;
  const int m0 = blockIdx.x * 128 + w * 32;

  f32x4 acc[2][8];
#pragma unroll
  for (int a = 0; a < 2; a++)
#pragma unroll
    for (int b = 0; b < 8; b++) acc[a][b] = (f32x4){0.f, 0.f, 0.f, 0.f};

  int n0 = m0 + lm;      if (n0 >= nrows) n0 = nrows - 1;
  int n1 = m0 + 16 + lm; if (n1 >= nrows) n1 = nrows - 1;
  const u16* hr0 = hb + (size_t)n0 * DD + lg * 8;
  const u16* hr1 = hb + (size_t)n1 * DD + lg * 8;
  const u16* wl = Wpk + l * 8;

#pragma unroll
  for (int ks = 0; ks < 4; ks++) {
    bf16x8 h0 = *(const bf16x8*)(hr0 + ks * 32);
    bf16x8 h1 = *(const bf16x8*)(hr1 + ks * 32);
#pragma unroll
    for (int nt = 0; nt < 8; nt++) {
      bf16x8 wf = *(const bf16x8*)(wl + (ks * 8 + nt) * 512);
      acc[0][nt] = __builtin_amdgcn_mfma_f32_16x16x32_bf16(wf, h0, acc[0][nt], 0, 0, 0);
      acc[1][nt] = __builtin_amdgcn_mfma_f32_16x16x32_bf16(wf, h1, acc[1][nt], 0, 0, 0);
    }
  }

#pragma unroll
  for (int mf = 0; mf < 2; mf++) {
    int node = m0 + mf * 16 + lm;
    if (node < nrows) {
      u16* dst = hp + (size_t)node * DD + lg * 4;
#pragma unroll
      for (int nt = 0; nt < 8; nt++) {
        float4 b4 = *(const float4*)(bvec + nt * 16 + lg * 4);
        f32x4 a = acc[mf][nt];
        float v0 = fmaxf(a[0] + b4.x, 0.f);
        float v1 = fmaxf(a[1] + b4.y, 0.f);
        float v2 = fmaxf(a[2] + b4.z, 0.f);
        float v3 = fmaxf(a[3] + b4.w, 0.f);
        uint2 o;
        o.x = (u32)f2bf(v0) | ((u32)f2bf(v1) << 16);
        o.y = (u32)f2bf(v2) | ((u32)f2bf(v3) << 16);
        *(uint2*)(dst + nt * 16) = o;
      }
    }
  }
}

// ---- GEMM 2: xb = hb@Ws + neigh@Wn + b (bf16 out, no relu) -----------------
__global__ __launch_bounds__(256, 2) void k_gemm_out(
    const u16* __restrict__ hb, const u16* __restrict__ gb,
    const u16* __restrict__ WpkS, const u16* __restrict__ WpkN,
    const float* __restrict__ bvec, u16* __restrict__ xb, int nrows)
{
  const int tid = threadIdx.x;
  const int w = tid >> 6, l = tid & 63;
  const int lg = l >> 4, lm = l & 15;
  const int m0 = blockIdx.x * 128 + w * 32;

  f32x4 acc[2][8];
#pragma unroll
  for (int a = 0; a < 2; a++)
#pragma unroll
    for (int b = 0; b < 8; b++) acc[a][b] = (f32x4){0.f, 0.f, 0.f, 0.f};

  int n0 = m0 + lm;      if (n0 >= nrows) n0 = nrows - 1;
  int n1 = m0 + 16 + lm; if (n1 >= nrows) n1 = nrows - 1;

#pragma unroll
  for (int pass = 0; pass < 2; pass++) {
    const u16* B = pass ? gb : hb;
    const u16* wl = (pass ? WpkN : WpkS) + l * 8;
    const u16* hr0 = B + (size_t)n0 * DD + lg * 8;
    const u16* hr1 = B + (size_t)n1 * DD + lg * 8;
#pragma unroll
    for (int ks = 0; ks < 4; ks++) {
      bf16x8 h0 = *(const bf16x8*)(hr0 + ks * 32);
      bf16x8 h1 = *(const bf16x8*)(hr1 + ks * 32);
#pragma unroll
      for (int nt = 0; nt < 8; nt++) {
        bf16x8 wf = *(const bf16x8*)(wl + (ks * 8 + nt) * 512);
        acc[0][nt] = __builtin_amdgcn_mfma_f32_16x16x32_bf16(wf, h0, acc[0][nt], 0, 0, 0);
        acc[1][nt] = __builtin_amdgcn_mfma_f32_16x16x32_bf16(wf, h1, acc[1][nt], 0, 0, 0);
      }
    }
  }

#pragma unroll
  for (int mf = 0; mf < 2; mf++) {
    int node = m0 + mf * 16 + lm;
    if (node < nrows) {
      u16* dst = xb + (size_t)node * DD + lg * 4;
#pragma unroll
      for (int nt = 0; nt < 8; nt++) {
        float4 b4 = *(const float4*)(bvec + nt * 16 + lg * 4);
        f32x4 a = acc[mf][nt];
        uint2 o;
        o.x = (u32)f2bf(a[0] + b4.x) | ((u32)f2bf(a[1] + b4.y) << 16);
        o.y = (u32)f2bf(a[2] + b4.z) | ((u32)f2bf(a[3] + b4.w) << 16);
        *(uint2*)(dst + nt * 16) = o;
      }
    }
  }
}

// ---- CSR build --------------------------------------------------------------
__global__ __launch_bounds__(256) void k_zero_i(int* p, int n) {
  int i = blockIdx.x * 256 + threadIdx.x;
  if (i < n) p[i] = 0;
}

// degree histogram + bucket histogram in one pass
__global__ __launch_bounds__(256) void k_hist(
    const int* __restrict__ dst, int* __restrict__ deg,
    int* __restrict__ bcnt, int E, int nbuk)
{
  __shared__ int cnt[MAXB];
  for (int i = threadIdx.x; i < MAXB; i += 256) cnt[i] = 0;
  __syncthreads();
  for (int e = blockIdx.x * 256 + threadIdx.x; e < E; e += gridDim.x * 256) {
    int d = dst[e];
    atomicAdd(&deg[d], 1);
    atomicAdd(&cnt[d >> BSH], 1);
  }
  __syncthreads();
  for (int i = threadIdx.x; i < nbuk; i += 256)
    if (cnt[i]) atomicAdd(&bcnt[i], cnt[i]);
}

// per-block exclusive scan of deg -> off, block sums to bs
__global__ __launch_bounds__(256) void k_scan1(
    const int* __restrict__ deg, int* __restrict__ off, int* __restrict__ bs, int n)
{
  __shared__ int sm[256];
  int i = blockIdx.x * 256 + threadIdx.x;
  int v = (i < n) ? deg[i] : 0;
  sm[threadIdx.x] = v;
  __syncthreads();
  int acc = v;
#pragma unroll
  for (int s = 1; s < 256; s <<= 1) {
    int t = (threadIdx.x >= s) ? sm[threadIdx.x - s] : 0;
    __syncthreads();
    acc += t;
    sm[threadIdx.x] = acc;
    __syncthreads();
  }
  if (i < n) off[i] = acc - v;
  if (threadIdx.x == 255) bs[blockIdx.x] = acc;
}

// parallel scan of block sums (nb <= 512)
__global__ __launch_bounds__(512) void k_scan2(int* bs, int nb, int* off, int n, int E) {
  __shared__ int sm[512];
  int t = threadIdx.x;
  int v = (t < nb) ? bs[t] : 0;
  sm[t] = v;
  __syncthreads();
  int acc = v;
#pragma unroll
  for (int s = 1; s < 512; s <<= 1) {
    int u = (t >= s) ? sm[t - s] : 0;
    __syncthreads();
    acc += u;
    sm[t] = acc;
    __syncthreads();
  }
  if (t < nb) bs[t] = acc - v;
  if (t == 0) off[n] = E;
}

__global__ __launch_bounds__(256) void k_scan3(
    int* __restrict__ off, const int* __restrict__ bs, int n)
{
  int i = blockIdx.x * 256 + threadIdx.x;
  if (i < n) off[i] += bs[blockIdx.x];
}

// scan bucket counts -> boff, init bcur (nbuk <= 256, one block)
__global__ __launch_bounds__(256) void k_bscan(
    const int* __restrict__ bcnt, int* __restrict__ boff,
    int* __restrict__ bcur, int nbuk, int E)
{
  __shared__ int sm[256];
  int t = threadIdx.x;
  int v = (t < nbuk) ? bcnt[t] : 0;
  sm[t] = v;
  __syncthreads();
  int acc = v;
#pragma unroll
  for (int s = 1; s < 256; s <<= 1) {
    int u = (t >= s) ? sm[t - s] : 0;
    __syncthreads();
    acc += u;
    sm[t] = acc;
    __syncthreads();
  }
  if (t < nbuk) { boff[t] = acc - v; bcur[t] = acc - v; }
  if (t == 0) boff[nbuk] = E;
}

// partition edges into dst-buckets; block-aggregated allocation, ranked writes
__global__ __launch_bounds__(256) void k_part(
    const int* __restrict__ src, const int* __restrict__ dst,
    int* __restrict__ bcur, int2* __restrict__ pairs, int E)
{
  __shared__ int cnt[MAXB];
  __shared__ int base[MAXB];
  int e = blockIdx.x * 256 + threadIdx.x;
  for (int i = threadIdx.x; i < MAXB; i += 256) cnt[i] = 0;
  __syncthreads();
  int d = 0, s = 0, b = 0, rank = 0;
  bool ok = (e < E);
  if (ok) {
    d = dst[e]; s = src[e]; b = d >> BSH;
    rank = atomicAdd(&cnt[b], 1);
  }
  __syncthreads();
  for (int i = threadIdx.x; i < MAXB; i += 256) {
    int c = cnt[i];
    base[i] = c ? atomicAdd(&bcur[i], c) : 0;
  }
  __syncthreads();
  if (ok) pairs[base[b] + rank] = make_int2(s, d);
}

// final scatter: per-bucket (4 blocks each), writes confined to bucket window
__global__ __launch_bounds__(256) void k_fscat(
    const int2* __restrict__ pairs, const int* __restrict__ boff,
    const int* __restrict__ off, int* __restrict__ cur,
    int* __restrict__ eidx)
{
  int b = blockIdx.x >> 2, part = blockIdx.x & 3;
  int lo = boff[b], hi = boff[b + 1];
  int c = hi - lo;
  int q0 = lo + ((c * part) >> 2);
  int q1 = lo + ((c * (part + 1)) >> 2);
  for (int i = q0 + threadIdx.x; i < q1; i += 256) {
    int2 p = pairs[i];
    int pos = off[p.y] + atomicAdd(&cur[p.y], 1);
    eidx[pos] = p.x;
  }
}

// ---- aggregate: neigh[d] = max(hp[d], max over in-edges), bf16, 8-deep -----
__global__ __launch_bounds__(256) void k_aggregate(
    const u32* __restrict__ hp, const int* __restrict__ off,
    const int* __restrict__ eidx, u32* __restrict__ nb, int nrows)
{
  int d = blockIdx.x * 4 + (threadIdx.x >> 6);
  if (d >= nrows) return;
  int lane = threadIdx.x & 63;
  u32 a = hp[(size_t)d * 64 + lane];
  int b = off[d], e = off[d + 1];
  int i = b;
  for (; i + 7 < e; i += 8) {
    int s0 = eidx[i],     s1 = eidx[i + 1], s2 = eidx[i + 2], s3 = eidx[i + 3];
    int s4 = eidx[i + 4], s5 = eidx[i + 5], s6 = eidx[i + 6], s7 = eidx[i + 7];
    u32 v0 = hp[(size_t)s0 * 64 + lane];
    u32 v1 = hp[(size_t)s1 * 64 + lane];
    u32 v2 = hp[(size_t)s2 * 64 + lane];
    u32 v3 = hp[(size_t)s3 * 64 + lane];
    u32 v4 = hp[(size_t)s4 * 64 + lane];
    u32 v5 = hp[(size_t)s5 * 64 + lane];
    u32 v6 = hp[(size_t)s6 * 64 + lane];
    u32 v7 = hp[(size_t)s7 * 64 + lane];
    a = bmax(a, bmax(bmax(bmax(v0, v1), bmax(v2, v3)),
                     bmax(bmax(v4, v5), bmax(v6, v7))));
  }
  for (; i + 1 < e; i += 2) {
    u32 v0 = hp[(size_t)eidx[i] * 64 + lane];
    u32 v1 = hp[(size_t)eidx[i + 1] * 64 + lane];
    a = bmax(a, bmax(v0, v1));
  }
  if (i < e) a = bmax(a, hp[(size_t)eidx[i] * 64 + lane]);
  nb[(size_t)d * 64 + lane] = a;
}

// ---- BN stats ---------------------------------------------------------------
__global__ __launch_bounds__(256) void k_stats(
    const u16* __restrict__ xb, float* __restrict__ parts, int nchunks)
{
  __shared__ float sm[256][8];
  int t = threadIdx.x;
  float s[8], q[8];
#pragma unroll
  for (int j = 0; j < 8; j++) { s[j] = 0.f; q[j] = 0.f; }
  for (int i = blockIdx.x * 256 + t; i < nchunks; i += gridDim.x * 256) {
    uint4 v = ((const uint4*)xb)[i];
    float f;
    f = bf2f_lo(v.x); s[0] += f; q[0] += f * f;
    f = bf2f_hi(v.x); s[1] += f; q[1] += f * f;
    f = bf2f_lo(v.y); s[2] += f; q[2] += f * f;
    f = bf2f_hi(v.y); s[3] += f; q[3] += f * f;
    f = bf2f_lo(v.z); s[4] += f; q[4] += f * f;
    f = bf2f_hi(v.z); s[5] += f; q[5] += f * f;
    f = bf2f_lo(v.w); s[6] += f; q[6] += f * f;
    f = bf2f_hi(v.w); s[7] += f; q[7] += f * f;
  }
#pragma unroll
  for (int j = 0; j < 8; j++) sm[t][j] = s[j];
  __syncthreads();
  if (t < 128) {
    int fc = t >> 3, j = t & 7;
    float a = 0.f;
#pragma unroll
    for (int g = 0; g < 16; g++) a += sm[g * 16 + fc][j];
    parts[blockIdx.x * 256 + t] = a;
  }
  __syncthreads();
#pragma unroll
  for (int j = 0; j < 8; j++) sm[t][j] = q[j];
  __syncthreads();
  if (t < 128) {
    int fc = t >> 3, j = t & 7;
    float a = 0.f;
#pragma unroll
    for (int g = 0; g < 16; g++) a += sm[g * 16 + fc][j];
    parts[blockIdx.x * 256 + 128 + t] = a;
  }
}

__global__ __launch_bounds__(256) void k_bn_prep(
    const float* __restrict__ parts, int nb,
    const float* __restrict__ gamma, const float* __restrict__ beta,
    float* __restrict__ sc, float* __restrict__ sh, float invN)
{
  __shared__ float sums[256];
  int t = threadIdx.x;
  int c = t & 127, q = t >> 7;
  float s = 0.f;
  for (int b = 0; b < nb; b++) s += parts[b * 256 + q * 128 + c];
  sums[t] = s;
  __syncthreads();
  if (t < 128) {
    float mean = sums[t] * invN;
    float var = sums[128 + t] * invN - mean * mean;
    float g = gamma[t] * rsqrtf(var + 1e-5f);
    sc[t] = g;
    sh[t] = beta[t] - mean * g;
  }
}

__global__ __launch_bounds__(256) void k_bn_apply(
    const u16* __restrict__ xb, u16* __restrict__ hb, float* __restrict__ out,
    const float* __restrict__ sc, const float* __restrict__ sh, int n8, int last)
{
  int i = blockIdx.x * 256 + threadIdx.x;
  if (i >= n8) return;
  uint4 v = ((const uint4*)xb)[i];
  int f0 = (i & 15) * 8;
  float4 c0 = *(const float4*)(sc + f0);
  float4 c1 = *(const float4*)(sc + f0 + 4);
  float4 h0 = *(const float4*)(sh + f0);
  float4 h1 = *(const float4*)(sh + f0 + 4);
  float y0 = fmaxf(fmaf(bf2f_lo(v.x), c0.x, h0.x), 0.f);
  float y1 = fmaxf(fmaf(bf2f_hi(v.x), c0.y, h0.y), 0.f);
  float y2 = fmaxf(fmaf(bf2f_lo(v.y), c0.z, h0.z), 0.f);
  float y3 = fmaxf(fmaf(bf2f_hi(v.y), c0.w, h0.w), 0.f);
  float y4 = fmaxf(fmaf(bf2f_lo(v.z), c1.x, h1.x), 0.f);
  float y5 = fmaxf(fmaf(bf2f_hi(v.z), c1.y, h1.y), 0.f);
  float y6 = fmaxf(fmaf(bf2f_lo(v.w), c1.z, h1.z), 0.f);
  float y7 = fmaxf(fmaf(bf2f_hi(v.w), c1.w, h1.w), 0.f);
  if (last) {
    float4* o = (float4*)out + 2 * (size_t)i;
    o[0] = make_float4(y0, y1, y2, y3);
    o[1] = make_float4(y4, y5, y6, y7);
  } else {
    uint4 o;
    o.x = (u32)f2bf(y0) | ((u32)f2bf(y1) << 16);
    o.y = (u32)f2bf(y2) | ((u32)f2bf(y3) << 16);
    o.z = (u32)f2bf(y4) | ((u32)f2bf(y5) << 16);
    o.w = (u32)f2bf(y6) | ((u32)f2bf(y7) << 16);
    ((uint4*)hb)[i] = o;
  }
}

// ---- launcher ---------------------------------------------------------------
extern "C" void kernel_launch(void* const* d_in, const int* in_sizes, int n_in,
                              void* d_out, int out_size, void* d_ws, size_t ws_size,
                              hipStream_t stream)
{
  const float* feat    = (const float*)d_in[0];
  const float* W_pool  = (const float*)d_in[1];
  const float* b_pool  = (const float*)d_in[2];
  const float* W_self  = (const float*)d_in[3];
  const float* W_neigh = (const float*)d_in[4];
  const float* bias    = (const float*)d_in[5];
  const float* gamma   = (const float*)d_in[6];
  const float* beta    = (const float*)d_in[7];
  const int*   src     = (const int*)d_in[8];
  const int*   dst     = (const int*)d_in[9];

  const int Nn = in_sizes[0] / DD;   // 100000
  const int E  = in_sizes[8];        // 1600000
  float* out = (float*)d_out;

  const size_t ND = (size_t)Nn * DD;
  u16*   hb    = (u16*)d_ws;                    // ND bf16
  u16*   hp    = hb + ND;                       // ND bf16 (also xb)
  u16*   nbuf  = hp + ND;                       // ND bf16
  u16*   Wpk   = nbuf + ND;                     // 9*16384 bf16
  float* parts = (float*)(Wpk + 9 * 16384);     // SB*256 f32
  float* sc    = parts + SB * 256;              // 128
  float* sh    = sc + DD;                       // 128
  int*   deg   = (int*)(sh + DD);               // Nn (also fscat cursor)
  int*   off   = deg + Nn;                      // Nn+2 (even pad)
  int*   bs    = off + Nn + 2;                  // 512
  int*   bcnt  = bs + 512;                      // MAXB
  int*   boff  = bcnt + MAXB;                   // MAXB+2
  int*   bcur  = boff + MAXB + 2;               // MAXB
  int2*  pairs = (int2*)(bcur + MAXB);          // E (8B aligned)
  int*   eidx  = (int*)(pairs + E);             // E

  const int nbuk = (Nn + 511) >> BSH;           // 196
  const int nsb  = (Nn + 255) / 256;            // 391
  const int gB   = (Nn + 127) / 128;
  const int eB   = (E + 255) / 256;
  const int aggB = (Nn + 3) / 4;
  const int n8   = Nn * (DD / 8);
  const int cB   = (n8 + 255) / 256;

  // one-time setup
  k_pack_w<<<72, 256, 0, stream>>>(W_pool, W_self, W_neigh, Wpk);
  k_cast<<<cB, 256, 0, stream>>>(feat, hb, n8);
  k_zero_i<<<nsb, 256, 0, stream>>>(deg, Nn);
  k_zero_i<<<1, 256, 0, stream>>>(bcnt, MAXB);
  k_hist<<<512, 256, 0, stream>>>(dst, deg, bcnt, E, nbuk);
  k_scan1<<<nsb, 256, 0, stream>>>(deg, off, bs, Nn);
  k_scan2<<<1, 512, 0, stream>>>(bs, nsb, off, Nn, E);
  k_scan3<<<nsb, 256, 0, stream>>>(off, bs, Nn);
  k_bscan<<<1, 256, 0, stream>>>(bcnt, boff, bcur, nbuk, E);
  k_part<<<eB, 256, 0, stream>>>(src, dst, bcur, pairs, E);
  k_zero_i<<<nsb, 256, 0, stream>>>(deg, Nn);   // reuse deg as cursor
  k_fscat<<<nbuk * 4, 256, 0, stream>>>(pairs, boff, off, deg, eidx);

  for (int l = 0; l < 3; l++) {
    const float* bp = b_pool + (size_t)l * DD;
    const float* bl = bias + (size_t)l * DD;
    k_gemm_pool<<<gB, 256, 0, stream>>>(hb, Wpk + (size_t)l * 16384, bp, hp, Nn);
    k_aggregate<<<aggB, 256, 0, stream>>>((const u32*)hp, off, eidx, (u32*)nbuf, Nn);
    k_gemm_out<<<gB, 256, 0, stream>>>(hb, nbuf, Wpk + (size_t)(3 + l) * 16384,
                                       Wpk + (size_t)(6 + l) * 16384, bl, hp, Nn);
    k_stats<<<SB, 256, 0, stream>>>(hp, parts, Nn * 16);
    k_bn_prep<<<1, 256, 0, stream>>>(parts, SB, gamma + (size_t)l * DD,
                                     beta + (size_t)l * DD, sc, sh, 1.0f / (float)Nn);
    k_bn_apply<<<cB, 256, 0, stream>>>(hp, hb, out, sc, sh, n8, l == 2);
  }
  (void)n_in; (void)out_size; (void)ws_size;
}

// Round 5
// 700.509 us; speedup vs baseline: 2.9526x; 1.2066x over previous
//
#include <hip/hip_runtime.h>

#define DD 128
#define SB 128    // stats partial blocks
#define MAXB 256  // max dst-buckets (supports N <= 131072)
#define BSH 9     // bucket = dst >> 9  (512 nodes/bucket)
#define PEB 4096  // edges per partition block

typedef unsigned short u16;
typedef unsigned int   u32;
typedef __attribute__((ext_vector_type(8))) short bf16x8;
typedef __attribute__((ext_vector_type(4))) float f32x4;

__device__ inline u16 f2bf(float x) {
  u32 u = __float_as_uint(x);
  u += 0x7fffu + ((u >> 16) & 1u);
  return (u16)(u >> 16);
}
__device__ inline float bf2f_lo(u32 w) { return __uint_as_float(w << 16); }
__device__ inline float bf2f_hi(u32 w) { return __uint_as_float(w & 0xffff0000u); }
__device__ inline u32 bmax(u32 a, u32 b) {
  u32 al = a & 0xffffu, bl = b & 0xffffu;
  u32 ah = a >> 16,     bh = b >> 16;
  u32 lo = al > bl ? al : bl;
  u32 hi = ah > bh ? ah : bh;
  return lo | (hi << 16);
}

// ---- pack 9 weight matrices (fp32 [k][n]) into MFMA A-frag layout, bf16 ----
__global__ __launch_bounds__(256) void k_pack_w(
    const float* __restrict__ Wp, const float* __restrict__ Wsf,
    const float* __restrict__ Wn, u16* __restrict__ Wpk)
{
  int g = blockIdx.x * 256 + threadIdx.x;      // 9 * 2048
  int m = g >> 11;
  if (m >= 9) return;
  int t = g & 2047;
  const float* W = (m < 3) ? Wp + (size_t)m * 16384
                 : (m < 6) ? Wsf + (size_t)(m - 3) * 16384
                           : Wn + (size_t)(m - 6) * 16384;
  int ks = t >> 9, nt = (t >> 6) & 7, l = t & 63;
  int kbase = ks * 32 + (l >> 4) * 8;
  int n = nt * 16 + (l & 15);
  u32 o[4];
#pragma unroll
  for (int p = 0; p < 4; p++) {
    u16 e0 = f2bf(W[(size_t)(kbase + 2 * p) * DD + n]);
    u16 e1 = f2bf(W[(size_t)(kbase + 2 * p + 1) * DD + n]);
    o[p] = (u32)e0 | ((u32)e1 << 16);
  }
  uint4* dst = (uint4*)(Wpk + (size_t)m * 16384 + (size_t)t * 8);
  *dst = make_uint4(o[0], o[1], o[2], o[3]);
}

// ---- fp32 -> bf16 cast ------------------------------------------------------
__global__ __launch_bounds__(256) void k_cast(
    const float* __restrict__ x, u16* __restrict__ y, int n8)
{
  int i = blockIdx.x * 256 + threadIdx.x;
  if (i >= n8) return;
  float4 a = ((const float4*)x)[2 * i];
  float4 b = ((const float4*)x)[2 * i + 1];
  uint4 o;
  o.x = (u32)f2bf(a.x) | ((u32)f2bf(a.y) << 16);
  o.y = (u32)f2bf(a.z) | ((u32)f2bf(a.w) << 16);
  o.z = (u32)f2bf(b.x) | ((u32)f2bf(b.y) << 16);
  o.w = (u32)f2bf(b.z) | ((u32)f2bf(b.w) << 16);
  ((uint4*)y)[i] = o;
}

// ---- GEMM 1: hp = relu(hb @ W + b), bf16 MFMA, no LDS ----------------------
__global__ __launch_bounds__(256, 2) void k_gemm_pool(
    const u16* __restrict__ hb, const u16* __restrict__ Wpk,
    const float* __restrict__ bvec, u16* __restrict__ hp, int nrows)
{
  const int tid = threadIdx.x;
  const int w = tid >> 6, l = tid & 63;
  const int lg = l >> 4, lm = l & 15;
  const int m0 = blockIdx.x * 128 + w * 32;

  f32x4 acc[2][8];
#pragma unroll
  for (int a = 0; a < 2; a++)
#pragma unroll
    for (int b = 0; b < 8; b++) acc[a][b] = (f32x4){0.f, 0.f, 0.f, 0.f};

  int n0 = m0 + lm;      if (n0 >= nrows) n0 = nrows - 1;
  int n1 = m0 + 16 + lm; if (n1 >= nrows) n1 = nrows - 1;
  const u16* hr0 = hb + (size_t)n0 * DD + lg * 8;
  const u16* hr1 = hb + (size_t)n1 * DD + lg * 8;
  const u16* wl = Wpk + l * 8;

#pragma unroll
  for (int ks = 0; ks < 4; ks++) {
    bf16x8 h0 = *(const bf16x8*)(hr0 + ks * 32);
    bf16x8 h1 = *(const bf16x8*)(hr1 + ks * 32);
#pragma unroll
    for (int nt = 0; nt < 8; nt++) {
      bf16x8 wf = *(const bf16x8*)(wl + (ks * 8 + nt) * 512);
      acc[0][nt] = __builtin_amdgcn_mfma_f32_16x16x32_bf16(wf, h0, acc[0][nt], 0, 0, 0);
      acc[1][nt] = __builtin_amdgcn_mfma_f32_16x16x32_bf16(wf, h1, acc[1][nt], 0, 0, 0);
    }
  }

#pragma unroll
  for (int mf = 0; mf < 2; mf++) {
    int node = m0 + mf * 16 + lm;
    if (node < nrows) {
      u16* dst = hp + (size_t)node * DD + lg * 4;
#pragma unroll
      for (int nt = 0; nt < 8; nt++) {
        float4 b4 = *(const float4*)(bvec + nt * 16 + lg * 4);
        f32x4 a = acc[mf][nt];
        float v0 = fmaxf(a[0] + b4.x, 0.f);
        float v1 = fmaxf(a[1] + b4.y, 0.f);
        float v2 = fmaxf(a[2] + b4.z, 0.f);
        float v3 = fmaxf(a[3] + b4.w, 0.f);
        uint2 o;
        o.x = (u32)f2bf(v0) | ((u32)f2bf(v1) << 16);
        o.y = (u32)f2bf(v2) | ((u32)f2bf(v3) << 16);
        *(uint2*)(dst + nt * 16) = o;
      }
    }
  }
}

// ---- GEMM 2: xb = hb@Ws + neigh@Wn + b (bf16 out, no relu) -----------------
__global__ __launch_bounds__(256, 2) void k_gemm_out(
    const u16* __restrict__ hb, const u16* __restrict__ gb,
    const u16* __restrict__ WpkS, const u16* __restrict__ WpkN,
    const float* __restrict__ bvec, u16* __restrict__ xb, int nrows)
{
  const int tid = threadIdx.x;
  const int w = tid >> 6, l = tid & 63;
  const int lg = l >> 4, lm = l & 15;
  const int m0 = blockIdx.x * 128 + w * 32;

  f32x4 acc[2][8];
#pragma unroll
  for (int a = 0; a < 2; a++)
#pragma unroll
    for (int b = 0; b < 8; b++) acc[a][b] = (f32x4){0.f, 0.f, 0.f, 0.f};

  int n0 = m0 + lm;      if (n0 >= nrows) n0 = nrows - 1;
  int n1 = m0 + 16 + lm; if (n1 >= nrows) n1 = nrows - 1;

#pragma unroll
  for (int pass = 0; pass < 2; pass++) {
    const u16* B = pass ? gb : hb;
    const u16* wl = (pass ? WpkN : WpkS) + l * 8;
    const u16* hr0 = B + (size_t)n0 * DD + lg * 8;
    const u16* hr1 = B + (size_t)n1 * DD + lg * 8;
#pragma unroll
    for (int ks = 0; ks < 4; ks++) {
      bf16x8 h0 = *(const bf16x8*)(hr0 + ks * 32);
      bf16x8 h1 = *(const bf16x8*)(hr1 + ks * 32);
#pragma unroll
      for (int nt = 0; nt < 8; nt++) {
        bf16x8 wf = *(const bf16x8*)(wl + (ks * 8 + nt) * 512);
        acc[0][nt] = __builtin_amdgcn_mfma_f32_16x16x32_bf16(wf, h0, acc[0][nt], 0, 0, 0);
        acc[1][nt] = __builtin_amdgcn_mfma_f32_16x16x32_bf16(wf, h1, acc[1][nt], 0, 0, 0);
      }
    }
  }

#pragma unroll
  for (int mf = 0; mf < 2; mf++) {
    int node = m0 + mf * 16 + lm;
    if (node < nrows) {
      u16* dst = xb + (size_t)node * DD + lg * 4;
#pragma unroll
      for (int nt = 0; nt < 8; nt++) {
        float4 b4 = *(const float4*)(bvec + nt * 16 + lg * 4);
        f32x4 a = acc[mf][nt];
        uint2 o;
        o.x = (u32)f2bf(a[0] + b4.x) | ((u32)f2bf(a[1] + b4.y) << 16);
        o.y = (u32)f2bf(a[2] + b4.z) | ((u32)f2bf(a[3] + b4.w) << 16);
        *(uint2*)(dst + nt * 16) = o;
      }
    }
  }
}

// ---- CSR build --------------------------------------------------------------
__global__ __launch_bounds__(256) void k_zero_i(int* p, int n) {
  int i = blockIdx.x * 256 + threadIdx.x;
  if (i < n) p[i] = 0;
}

// degree histogram + bucket histogram in one pass
__global__ __launch_bounds__(256) void k_hist(
    const int* __restrict__ dst, int* __restrict__ deg,
    int* __restrict__ bcnt, int E, int nbuk)
{
  __shared__ int cnt[MAXB];
  for (int i = threadIdx.x; i < MAXB; i += 256) cnt[i] = 0;
  __syncthreads();
  for (int e = blockIdx.x * 256 + threadIdx.x; e < E; e += gridDim.x * 256) {
    int d = dst[e];
    atomicAdd(&deg[d], 1);
    atomicAdd(&cnt[d >> BSH], 1);
  }
  __syncthreads();
  for (int i = threadIdx.x; i < nbuk; i += 256)
    if (cnt[i]) atomicAdd(&bcnt[i], cnt[i]);
}

// per-block exclusive scan of deg -> off, block sums to bs
__global__ __launch_bounds__(256) void k_scan1(
    const int* __restrict__ deg, int* __restrict__ off, int* __restrict__ bs, int n)
{
  __shared__ int sm[256];
  int i = blockIdx.x * 256 + threadIdx.x;
  int v = (i < n) ? deg[i] : 0;
  sm[threadIdx.x] = v;
  __syncthreads();
  int acc = v;
#pragma unroll
  for (int s = 1; s < 256; s <<= 1) {
    int t = (threadIdx.x >= s) ? sm[threadIdx.x - s] : 0;
    __syncthreads();
    acc += t;
    sm[threadIdx.x] = acc;
    __syncthreads();
  }
  if (i < n) off[i] = acc - v;
  if (threadIdx.x == 255) bs[blockIdx.x] = acc;
}

// parallel scan of block sums (nb <= 512)
__global__ __launch_bounds__(512) void k_scan2(int* bs, int nb, int* off, int n, int E) {
  __shared__ int sm[512];
  int t = threadIdx.x;
  int v = (t < nb) ? bs[t] : 0;
  sm[t] = v;
  __syncthreads();
  int acc = v;
#pragma unroll
  for (int s = 1; s < 512; s <<= 1) {
    int u = (t >= s) ? sm[t - s] : 0;
    __syncthreads();
    acc += u;
    sm[t] = acc;
    __syncthreads();
  }
  if (t < nb) bs[t] = acc - v;
  if (t == 0) off[n] = E;
}

__global__ __launch_bounds__(256) void k_scan3(
    int* __restrict__ off, const int* __restrict__ bs, int n)
{
  int i = blockIdx.x * 256 + threadIdx.x;
  if (i < n) off[i] += bs[blockIdx.x];
}

// scan bucket counts -> boff, init bcur (nbuk <= 256, one block)
__global__ __launch_bounds__(256) void k_bscan(
    const int* __restrict__ bcnt, int* __restrict__ boff,
    int* __restrict__ bcur, int nbuk, int E)
{
  __shared__ int sm[256];
  int t = threadIdx.x;
  int v = (t < nbuk) ? bcnt[t] : 0;
  sm[t] = v;
  __syncthreads();
  int acc = v;
#pragma unroll
  for (int s = 1; s < 256; s <<= 1) {
    int u = (t >= s) ? sm[t - s] : 0;
    __syncthreads();
    acc += u;
    sm[t] = acc;
    __syncthreads();
  }
  if (t < nbuk) { boff[t] = acc - v; bcur[t] = acc - v; }
  if (t == 0) boff[nbuk] = E;
}

// partition edges into dst-buckets; 4096 edges/block, two-phase LDS hist ->
// ONE global atomicAdd per (block,bucket) -> ranked writes
__global__ __launch_bounds__(256) void k_part(
    const int* __restrict__ src, const int* __restrict__ dst,
    int* __restrict__ bcur, int2* __restrict__ pairs, int E)
{
  __shared__ int cnt[MAXB];
  __shared__ int base[MAXB];
  const int e0 = blockIdx.x * PEB;
  const int e1 = min(e0 + PEB, E);
  for (int i = threadIdx.x; i < MAXB; i += 256) cnt[i] = 0;
  __syncthreads();
  for (int e = e0 + threadIdx.x; e < e1; e += 256)
    atomicAdd(&cnt[dst[e] >> BSH], 1);
  __syncthreads();
  for (int i = threadIdx.x; i < MAXB; i += 256) {
    int c = cnt[i];
    base[i] = c ? atomicAdd(&bcur[i], c) : 0;
    cnt[i] = 0;
  }
  __syncthreads();
  for (int e = e0 + threadIdx.x; e < e1; e += 256) {
    int d = dst[e], s = src[e];
    int b = d >> BSH;
    int r = atomicAdd(&cnt[b], 1);
    pairs[base[b] + r] = make_int2(s, d);
  }
}

// final scatter: per-bucket (4 blocks each), writes confined to bucket window
__global__ __launch_bounds__(256) void k_fscat(
    const int2* __restrict__ pairs, const int* __restrict__ boff,
    const int* __restrict__ off, int* __restrict__ cur,
    int* __restrict__ eidx)
{
  int b = blockIdx.x >> 2, part = blockIdx.x & 3;
  int lo = boff[b], hi = boff[b + 1];
  int c = hi - lo;
  int q0 = lo + ((c * part) >> 2);
  int q1 = lo + ((c * (part + 1)) >> 2);
  for (int i = q0 + threadIdx.x; i < q1; i += 256) {
    int2 p = pairs[i];
    int pos = off[p.y] + atomicAdd(&cur[p.y], 1);
    eidx[pos] = p.x;
  }
}

// ---- aggregate: neigh[d] = max(hp[d], max over in-edges), bf16, 8-deep -----
__global__ __launch_bounds__(256) void k_aggregate(
    const u32* __restrict__ hp, const int* __restrict__ off,
    const int* __restrict__ eidx, u32* __restrict__ nb, int nrows)
{
  int d = blockIdx.x * 4 + (threadIdx.x >> 6);
  if (d >= nrows) return;
  int lane = threadIdx.x & 63;
  u32 a = hp[(size_t)d * 64 + lane];
  int b = off[d], e = off[d + 1];
  int i = b;
  for (; i + 7 < e; i += 8) {
    int s0 = eidx[i],     s1 = eidx[i + 1], s2 = eidx[i + 2], s3 = eidx[i + 3];
    int s4 = eidx[i + 4], s5 = eidx[i + 5], s6 = eidx[i + 6], s7 = eidx[i + 7];
    u32 v0 = hp[(size_t)s0 * 64 + lane];
    u32 v1 = hp[(size_t)s1 * 64 + lane];
    u32 v2 = hp[(size_t)s2 * 64 + lane];
    u32 v3 = hp[(size_t)s3 * 64 + lane];
    u32 v4 = hp[(size_t)s4 * 64 + lane];
    u32 v5 = hp[(size_t)s5 * 64 + lane];
    u32 v6 = hp[(size_t)s6 * 64 + lane];
    u32 v7 = hp[(size_t)s7 * 64 + lane];
    a = bmax(a, bmax(bmax(bmax(v0, v1), bmax(v2, v3)),
                     bmax(bmax(v4, v5), bmax(v6, v7))));
  }
  for (; i + 1 < e; i += 2) {
    u32 v0 = hp[(size_t)eidx[i] * 64 + lane];
    u32 v1 = hp[(size_t)eidx[i + 1] * 64 + lane];
    a = bmax(a, bmax(v0, v1));
  }
  if (i < e) a = bmax(a, hp[(size_t)eidx[i] * 64 + lane]);
  nb[(size_t)d * 64 + lane] = a;
}

// ---- BN stats ---------------------------------------------------------------
__global__ __launch_bounds__(256) void k_stats(
    const u16* __restrict__ xb, float* __restrict__ parts, int nchunks)
{
  __shared__ float sm[256][8];
  int t = threadIdx.x;
  float s[8], q[8];
#pragma unroll
  for (int j = 0; j < 8; j++) { s[j] = 0.f; q[j] = 0.f; }
  for (int i = blockIdx.x * 256 + t; i < nchunks; i += gridDim.x * 256) {
    uint4 v = ((const uint4*)xb)[i];
    float f;
    f = bf2f_lo(v.x); s[0] += f; q[0] += f * f;
    f = bf2f_hi(v.x); s[1] += f; q[1] += f * f;
    f = bf2f_lo(v.y); s[2] += f; q[2] += f * f;
    f = bf2f_hi(v.y); s[3] += f; q[3] += f * f;
    f = bf2f_lo(v.z); s[4] += f; q[4] += f * f;
    f = bf2f_hi(v.z); s[5] += f; q[5] += f * f;
    f = bf2f_lo(v.w); s[6] += f; q[6] += f * f;
    f = bf2f_hi(v.w); s[7] += f; q[7] += f * f;
  }
#pragma unroll
  for (int j = 0; j < 8; j++) sm[t][j] = s[j];
  __syncthreads();
  if (t < 128) {
    int fc = t >> 3, j = t & 7;
    float a = 0.f;
#pragma unroll
    for (int g = 0; g < 16; g++) a += sm[g * 16 + fc][j];
    parts[blockIdx.x * 256 + t] = a;
  }
  __syncthreads();
#pragma unroll
  for (int j = 0; j < 8; j++) sm[t][j] = q[j];
  __syncthreads();
  if (t < 128) {
    int fc = t >> 3, j = t & 7;
    float a = 0.f;
#pragma unroll
    for (int g = 0; g < 16; g++) a += sm[g * 16 + fc][j];
    parts[blockIdx.x * 256 + 128 + t] = a;
  }
}

__global__ __launch_bounds__(256) void k_bn_prep(
    const float* __restrict__ parts, int nb,
    const float* __restrict__ gamma, const float* __restrict__ beta,
    float* __restrict__ sc, float* __restrict__ sh, float invN)
{
  __shared__ float sums[256];
  int t = threadIdx.x;
  int c = t & 127, q = t >> 7;
  float s = 0.f;
  for (int b = 0; b < nb; b++) s += parts[b * 256 + q * 128 + c];
  sums[t] = s;
  __syncthreads();
  if (t < 128) {
    float mean = sums[t] * invN;
    float var = sums[128 + t] * invN - mean * mean;
    float g = gamma[t] * rsqrtf(var + 1e-5f);
    sc[t] = g;
    sh[t] = beta[t] - mean * g;
  }
}

__global__ __launch_bounds__(256) void k_bn_apply(
    const u16* __restrict__ xb, u16* __restrict__ hb, float* __restrict__ out,
    const float* __restrict__ sc, const float* __restrict__ sh, int n8, int last)
{
  int i = blockIdx.x * 256 + threadIdx.x;
  if (i >= n8) return;
  uint4 v = ((const uint4*)xb)[i];
  int f0 = (i & 15) * 8;
  float4 c0 = *(const float4*)(sc + f0);
  float4 c1 = *(const float4*)(sc + f0 + 4);
  float4 h0 = *(const float4*)(sh + f0);
  float4 h1 = *(const float4*)(sh + f0 + 4);
  float y0 = fmaxf(fmaf(bf2f_lo(v.x), c0.x, h0.x), 0.f);
  float y1 = fmaxf(fmaf(bf2f_hi(v.x), c0.y, h0.y), 0.f);
  float y2 = fmaxf(fmaf(bf2f_lo(v.y), c0.z, h0.z), 0.f);
  float y3 = fmaxf(fmaf(bf2f_hi(v.y), c0.w, h0.w), 0.f);
  float y4 = fmaxf(fmaf(bf2f_lo(v.z), c1.x, h1.x), 0.f);
  float y5 = fmaxf(fmaf(bf2f_hi(v.z), c1.y, h1.y), 0.f);
  float y6 = fmaxf(fmaf(bf2f_lo(v.w), c1.z, h1.z), 0.f);
  float y7 = fmaxf(fmaf(bf2f_hi(v.w), c1.w, h1.w), 0.f);
  if (last) {
    float4* o = (float4*)out + 2 * (size_t)i;
    o[0] = make_float4(y0, y1, y2, y3);
    o[1] = make_float4(y4, y5, y6, y7);
  } else {
    uint4 o;
    o.x = (u32)f2bf(y0) | ((u32)f2bf(y1) << 16);
    o.y = (u32)f2bf(y2) | ((u32)f2bf(y3) << 16);
    o.z = (u32)f2bf(y4) | ((u32)f2bf(y5) << 16);
    o.w = (u32)f2bf(y6) | ((u32)f2bf(y7) << 16);
    ((uint4*)hb)[i] = o;
  }
}

// ---- launcher ---------------------------------------------------------------
extern "C" void kernel_launch(void* const* d_in, const int* in_sizes, int n_in,
                              void* d_out, int out_size, void* d_ws, size_t ws_size,
                              hipStream_t stream)
{
  const float* feat    = (const float*)d_in[0];
  const float* W_pool  = (const float*)d_in[1];
  const float* b_pool  = (const float*)d_in[2];
  const float* W_self  = (const float*)d_in[3];
  const float* W_neigh = (const float*)d_in[4];
  const float* bias    = (const float*)d_in[5];
  const float* gamma   = (const float*)d_in[6];
  const float* beta    = (const float*)d_in[7];
  const int*   src     = (const int*)d_in[8];
  const int*   dst     = (const int*)d_in[9];

  const int Nn = in_sizes[0] / DD;   // 100000
  const int E  = in_sizes[8];        // 1600000
  float* out = (float*)d_out;

  const size_t ND = (size_t)Nn * DD;
  u16*   hb    = (u16*)d_ws;                    // ND bf16
  u16*   hp    = hb + ND;                       // ND bf16 (also xb)
  u16*   nbuf  = hp + ND;                       // ND bf16
  u16*   Wpk   = nbuf + ND;                     // 9*16384 bf16
  float* parts = (float*)(Wpk + 9 * 16384);     // SB*256 f32
  float* sc    = parts + SB * 256;              // 128
  float* sh    = sc + DD;                       // 128
  int*   deg   = (int*)(sh + DD);               // Nn (also fscat cursor)
  int*   off   = deg + Nn;                      // Nn+2 (even pad)
  int*   bs    = off + Nn + 2;                  // 512
  int*   bcnt  = bs + 512;                      // MAXB
  int*   boff  = bcnt + MAXB;                   // MAXB+2
  int*   bcur  = boff + MAXB + 2;               // MAXB
  int2*  pairs = (int2*)(bcur + MAXB);          // E (8B aligned)
  int*   eidx  = (int*)(pairs + E);             // E

  const int nbuk = (Nn + 511) >> BSH;           // 196
  const int nsb  = (Nn + 255) / 256;            // 391
  const int gB   = (Nn + 127) / 128;
  const int eB   = (E + 255) / 256;
  const int pB   = (E + PEB - 1) / PEB;         // 391
  const int aggB = (Nn + 3) / 4;
  const int n8   = Nn * (DD / 8);
  const int cB   = (n8 + 255) / 256;

  // one-time setup
  k_pack_w<<<72, 256, 0, stream>>>(W_pool, W_self, W_neigh, Wpk);
  k_cast<<<cB, 256, 0, stream>>>(feat, hb, n8);
  k_zero_i<<<nsb, 256, 0, stream>>>(deg, Nn);
  k_zero_i<<<1, 256, 0, stream>>>(bcnt, MAXB);
  k_hist<<<512, 256, 0, stream>>>(dst, deg, bcnt, E, nbuk);
  k_scan1<<<nsb, 256, 0, stream>>>(deg, off, bs, Nn);
  k_scan2<<<1, 512, 0, stream>>>(bs, nsb, off, Nn, E);
  k_scan3<<<nsb, 256, 0, stream>>>(off, bs, Nn);
  k_bscan<<<1, 256, 0, stream>>>(bcnt, boff, bcur, nbuk, E);
  k_part<<<pB, 256, 0, stream>>>(src, dst, bcur, pairs, E);
  k_zero_i<<<nsb, 256, 0, stream>>>(deg, Nn);   // reuse deg as cursor
  k_fscat<<<nbuk * 4, 256, 0, stream>>>(pairs, boff, off, deg, eidx);

  for (int l = 0; l < 3; l++) {
    const float* bp = b_pool + (size_t)l * DD;
    const float* bl = bias + (size_t)l * DD;
    k_gemm_pool<<<gB, 256, 0, stream>>>(hb, Wpk + (size_t)l * 16384, bp, hp, Nn);
    k_aggregate<<<aggB, 256, 0, stream>>>((const u32*)hp, off, eidx, (u32*)nbuf, Nn);
    k_gemm_out<<<gB, 256, 0, stream>>>(hb, nbuf, Wpk + (size_t)(3 + l) * 16384,
                                       Wpk + (size_t)(6 + l) * 16384, bl, hp, Nn);
    k_stats<<<SB, 256, 0, stream>>>(hp, parts, Nn * 16);
    k_bn_prep<<<1, 256, 0, stream>>>(parts, SB, gamma + (size_t)l * DD,
                                     beta + (size_t)l * DD, sc, sh, 1.0f / (float)Nn);
    k_bn_apply<<<cB, 256, 0, stream>>>(hp, hb, out, sc, sh, n8, l == 2);
  }
  (void)n_in; (void)out_size; (void)ws_size;
}

// Round 6
// 602.117 us; speedup vs baseline: 3.4351x; 1.1634x over previous
//
#include <hip/hip_runtime.h>

#define DD 128
#define SB 128    // stats partial blocks
#define MAXB 256  // max dst-buckets (supports N <= 131072)
#define BSH 9     // bucket = dst >> 9  (512 nodes/bucket)
#define PEB 4096  // edges per partition block

typedef unsigned short u16;
typedef unsigned int   u32;
typedef __attribute__((ext_vector_type(8))) short bf16x8;
typedef __attribute__((ext_vector_type(4))) float f32x4;

__device__ inline u16 f2bf(float x) {
  u32 u = __float_as_uint(x);
  u += 0x7fffu + ((u >> 16) & 1u);
  return (u16)(u >> 16);
}
__device__ inline float bf2f_lo(u32 w) { return __uint_as_float(w << 16); }
__device__ inline float bf2f_hi(u32 w) { return __uint_as_float(w & 0xffff0000u); }
__device__ inline u32 bmax(u32 a, u32 b) {
  u32 al = a & 0xffffu, bl = b & 0xffffu;
  u32 ah = a >> 16,     bh = b >> 16;
  u32 lo = al > bl ? al : bl;
  u32 hi = ah > bh ? ah : bh;
  return lo | (hi << 16);
}

// ---- pack 9 weight matrices (fp32 [k][n]) into MFMA A-frag layout, bf16 ----
__global__ __launch_bounds__(256) void k_pack_w(
    const float* __restrict__ Wp, const float* __restrict__ Wsf,
    const float* __restrict__ Wn, u16* __restrict__ Wpk)
{
  int g = blockIdx.x * 256 + threadIdx.x;      // 9 * 2048
  int m = g >> 11;
  if (m >= 9) return;
  int t = g & 2047;
  const float* W = (m < 3) ? Wp + (size_t)m * 16384
                 : (m < 6) ? Wsf + (size_t)(m - 3) * 16384
                           : Wn + (size_t)(m - 6) * 16384;
  int ks = t >> 9, nt = (t >> 6) & 7, l = t & 63;
  int kbase = ks * 32 + (l >> 4) * 8;
  int n = nt * 16 + (l & 15);
  u32 o[4];
#pragma unroll
  for (int p = 0; p < 4; p++) {
    u16 e0 = f2bf(W[(size_t)(kbase + 2 * p) * DD + n]);
    u16 e1 = f2bf(W[(size_t)(kbase + 2 * p + 1) * DD + n]);
    o[p] = (u32)e0 | ((u32)e1 << 16);
  }
  uint4* dst = (uint4*)(Wpk + (size_t)m * 16384 + (size_t)t * 8);
  *dst = make_uint4(o[0], o[1], o[2], o[3]);
}

// ---- fp32 -> bf16 cast ------------------------------------------------------
__global__ __launch_bounds__(256) void k_cast(
    const float* __restrict__ x, u16* __restrict__ y, int n8)
{
  int i = blockIdx.x * 256 + threadIdx.x;
  if (i >= n8) return;
  float4 a = ((const float4*)x)[2 * i];
  float4 b = ((const float4*)x)[2 * i + 1];
  uint4 o;
  o.x = (u32)f2bf(a.x) | ((u32)f2bf(a.y) << 16);
  o.y = (u32)f2bf(a.z) | ((u32)f2bf(a.w) << 16);
  o.z = (u32)f2bf(b.x) | ((u32)f2bf(b.y) << 16);
  o.w = (u32)f2bf(b.z) | ((u32)f2bf(b.w) << 16);
  ((uint4*)y)[i] = o;
}

// ---- GEMM 1: hp = relu(hb @ W + b), bf16 MFMA, no LDS ----------------------
__global__ __launch_bounds__(256, 2) void k_gemm_pool(
    const u16* __restrict__ hb, const u16* __restrict__ Wpk,
    const float* __restrict__ bvec, u16* __restrict__ hp, int nrows)
{
  const int tid = threadIdx.x;
  const int w = tid >> 6, l = tid & 63;
  const int lg = l >> 4, lm = l & 15;
  const int m0 = blockIdx.x * 128 + w * 32;

  f32x4 acc[2][8];
#pragma unroll
  for (int a = 0; a < 2; a++)
#pragma unroll
    for (int b = 0; b < 8; b++) acc[a][b] = (f32x4){0.f, 0.f, 0.f, 0.f};

  int n0 = m0 + lm;      if (n0 >= nrows) n0 = nrows - 1;
  int n1 = m0 + 16 + lm; if (n1 >= nrows) n1 = nrows - 1;
  const u16* hr0 = hb + (size_t)n0 * DD + lg * 8;
  const u16* hr1 = hb + (size_t)n1 * DD + lg * 8;
  const u16* wl = Wpk + l * 8;

#pragma unroll
  for (int ks = 0; ks < 4; ks++) {
    bf16x8 h0 = *(const bf16x8*)(hr0 + ks * 32);
    bf16x8 h1 = *(const bf16x8*)(hr1 + ks * 32);
#pragma unroll
    for (int nt = 0; nt < 8; nt++) {
      bf16x8 wf = *(const bf16x8*)(wl + (ks * 8 + nt) * 512);
      acc[0][nt] = __builtin_amdgcn_mfma_f32_16x16x32_bf16(wf, h0, acc[0][nt], 0, 0, 0);
      acc[1][nt] = __builtin_amdgcn_mfma_f32_16x16x32_bf16(wf, h1, acc[1][nt], 0, 0, 0);
    }
  }

#pragma unroll
  for (int mf = 0; mf < 2; mf++) {
    int node = m0 + mf * 16 + lm;
    if (node < nrows) {
      u16* dst = hp + (size_t)node * DD + lg * 4;
#pragma unroll
      for (int nt = 0; nt < 8; nt++) {
        float4 b4 = *(const float4*)(bvec + nt * 16 + lg * 4);
        f32x4 a = acc[mf][nt];
        float v0 = fmaxf(a[0] + b4.x, 0.f);
        float v1 = fmaxf(a[1] + b4.y, 0.f);
        float v2 = fmaxf(a[2] + b4.z, 0.f);
        float v3 = fmaxf(a[3] + b4.w, 0.f);
        uint2 o;
        o.x = (u32)f2bf(v0) | ((u32)f2bf(v1) << 16);
        o.y = (u32)f2bf(v2) | ((u32)f2bf(v3) << 16);
        *(uint2*)(dst + nt * 16) = o;
      }
    }
  }
}

// ---- GEMM 2: xb = hb@Ws + neigh@Wn + b (bf16 out, no relu) -----------------
__global__ __launch_bounds__(256, 2) void k_gemm_out(
    const u16* __restrict__ hb, const u16* __restrict__ gb,
    const u16* __restrict__ WpkS, const u16* __restrict__ WpkN,
    const float* __restrict__ bvec, u16* __restrict__ xb, int nrows)
{
  const int tid = threadIdx.x;
  const int w = tid >> 6, l = tid & 63;
  const int lg = l >> 4, lm = l & 15;
  const int m0 = blockIdx.x * 128 + w * 32;

  f32x4 acc[2][8];
#pragma unroll
  for (int a = 0; a < 2; a++)
#pragma unroll
    for (int b = 0; b < 8; b++) acc[a][b] = (f32x4){0.f, 0.f, 0.f, 0.f};

  int n0 = m0 + lm;      if (n0 >= nrows) n0 = nrows - 1;
  int n1 = m0 + 16 + lm; if (n1 >= nrows) n1 = nrows - 1;

#pragma unroll
  for (int pass = 0; pass < 2; pass++) {
    const u16* B = pass ? gb : hb;
    const u16* wl = (pass ? WpkN : WpkS) + l * 8;
    const u16* hr0 = B + (size_t)n0 * DD + lg * 8;
    const u16* hr1 = B + (size_t)n1 * DD + lg * 8;
#pragma unroll
    for (int ks = 0; ks < 4; ks++) {
      bf16x8 h0 = *(const bf16x8*)(hr0 + ks * 32);
      bf16x8 h1 = *(const bf16x8*)(hr1 + ks * 32);
#pragma unroll
      for (int nt = 0; nt < 8; nt++) {
        bf16x8 wf = *(const bf16x8*)(wl + (ks * 8 + nt) * 512);
        acc[0][nt] = __builtin_amdgcn_mfma_f32_16x16x32_bf16(wf, h0, acc[0][nt], 0, 0, 0);
        acc[1][nt] = __builtin_amdgcn_mfma_f32_16x16x32_bf16(wf, h1, acc[1][nt], 0, 0, 0);
      }
    }
  }

#pragma unroll
  for (int mf = 0; mf < 2; mf++) {
    int node = m0 + mf * 16 + lm;
    if (node < nrows) {
      u16* dst = xb + (size_t)node * DD + lg * 4;
#pragma unroll
      for (int nt = 0; nt < 8; nt++) {
        float4 b4 = *(const float4*)(bvec + nt * 16 + lg * 4);
        f32x4 a = acc[mf][nt];
        uint2 o;
        o.x = (u32)f2bf(a[0] + b4.x) | ((u32)f2bf(a[1] + b4.y) << 16);
        o.y = (u32)f2bf(a[2] + b4.z) | ((u32)f2bf(a[3] + b4.w) << 16);
        *(uint2*)(dst + nt * 16) = o;
      }
    }
  }
}

// ---- CSR build --------------------------------------------------------------
__global__ __launch_bounds__(256) void k_zero_i(int* p, int n) {
  int i = blockIdx.x * 256 + threadIdx.x;
  if (i < n) p[i] = 0;
}

// bucket-only histogram: LDS aggregation, one global atomic per (block,bucket)
__global__ __launch_bounds__(256) void k_histb(
    const int* __restrict__ dst, int* __restrict__ bcnt, int E)
{
  __shared__ int cnt[MAXB];
  const int e0 = blockIdx.x * PEB;
  const int e1 = min(e0 + PEB, E);
  for (int i = threadIdx.x; i < MAXB; i += 256) cnt[i] = 0;
  __syncthreads();
  for (int e = e0 + threadIdx.x; e < e1; e += 256)
    atomicAdd(&cnt[dst[e] >> BSH], 1);
  __syncthreads();
  for (int i = threadIdx.x; i < MAXB; i += 256)
    if (cnt[i]) atomicAdd(&bcnt[i], cnt[i]);
}

// scan bucket counts -> boff, init bcur (nbuk <= 256, one block)
__global__ __launch_bounds__(256) void k_bscan(
    const int* __restrict__ bcnt, int* __restrict__ boff,
    int* __restrict__ bcur, int nbuk, int E)
{
  __shared__ int sm[256];
  int t = threadIdx.x;
  int v = (t < nbuk) ? bcnt[t] : 0;
  sm[t] = v;
  __syncthreads();
  int acc = v;
#pragma unroll
  for (int s = 1; s < 256; s <<= 1) {
    int u = (t >= s) ? sm[t - s] : 0;
    __syncthreads();
    acc += u;
    sm[t] = acc;
    __syncthreads();
  }
  if (t < nbuk) { boff[t] = acc - v; bcur[t] = acc - v; }
  if (t == 0) boff[nbuk] = E;
}

// partition edges into dst-buckets; 4096 edges/block, two-phase LDS hist ->
// ONE global atomicAdd per (block,bucket) -> ranked writes
__global__ __launch_bounds__(256) void k_part(
    const int* __restrict__ src, const int* __restrict__ dst,
    int* __restrict__ bcur, int2* __restrict__ pairs, int E)
{
  __shared__ int cnt[MAXB];
  __shared__ int base[MAXB];
  const int e0 = blockIdx.x * PEB;
  const int e1 = min(e0 + PEB, E);
  for (int i = threadIdx.x; i < MAXB; i += 256) cnt[i] = 0;
  __syncthreads();
  for (int e = e0 + threadIdx.x; e < e1; e += 256)
    atomicAdd(&cnt[dst[e] >> BSH], 1);
  __syncthreads();
  for (int i = threadIdx.x; i < MAXB; i += 256) {
    int c = cnt[i];
    base[i] = c ? atomicAdd(&bcur[i], c) : 0;
    cnt[i] = 0;
  }
  __syncthreads();
  for (int e = e0 + threadIdx.x; e < e1; e += 256) {
    int d = dst[e], s = src[e];
    int b = d >> BSH;
    int r = atomicAdd(&cnt[b], 1);
    pairs[base[b] + r] = make_int2(s, d);
  }
}

// per-bucket CSR finalize: LDS degree count -> local scan -> off write ->
// LDS-cursor scatter into eidx. One block per bucket; all counters in LDS.
__global__ __launch_bounds__(256) void k_csr(
    const int2* __restrict__ pairs, const int* __restrict__ boff,
    int* __restrict__ off, int* __restrict__ eidx, int nrows, int nbuk)
{
  __shared__ int cnt[512];
  __shared__ int ps[256];
  const int b = blockIdx.x;
  const int lo = boff[b], hi = boff[b + 1];
  const int t = threadIdx.x;
  cnt[t] = 0; cnt[t + 256] = 0;
  __syncthreads();
  for (int i = lo + t; i < hi; i += 256)
    atomicAdd(&cnt[pairs[i].y & 511], 1);
  __syncthreads();
  // exclusive scan over 512 counters (pairwise + 256-scan)
  int c0 = cnt[2 * t], c1 = cnt[2 * t + 1];
  ps[t] = c0 + c1;
  __syncthreads();
  int acc = ps[t];
#pragma unroll
  for (int s = 1; s < 256; s <<= 1) {
    int u = (t >= s) ? ps[t - s] : 0;
    __syncthreads();
    acc += u;
    ps[t] = acc;
    __syncthreads();
  }
  int base = lo + acc - (c0 + c1);   // global exclusive offset for node 2t
  int node0 = (b << BSH) + 2 * t;
  if (node0 < nrows)     off[node0]     = base;
  if (node0 + 1 < nrows) off[node0 + 1] = base + c0;
  if (b == nbuk - 1 && t == 0) off[nrows] = hi;
  // reuse cnt as global-position cursors
  cnt[2 * t]     = base;
  cnt[2 * t + 1] = base + c0;
  __syncthreads();
  for (int i = lo + t; i < hi; i += 256) {
    int2 p = pairs[i];
    int pos = atomicAdd(&cnt[p.y & 511], 1);
    eidx[pos] = p.x;
  }
}

// ---- aggregate: neigh[d] = max(hp[d], max over in-edges), bf16, 8-deep -----
__global__ __launch_bounds__(256) void k_aggregate(
    const u32* __restrict__ hp, const int* __restrict__ off,
    const int* __restrict__ eidx, u32* __restrict__ nb, int nrows)
{
  int d = blockIdx.x * 4 + (threadIdx.x >> 6);
  if (d >= nrows) return;
  int lane = threadIdx.x & 63;
  u32 a = hp[(size_t)d * 64 + lane];
  int b = off[d], e = off[d + 1];
  int i = b;
  for (; i + 7 < e; i += 8) {
    int s0 = eidx[i],     s1 = eidx[i + 1], s2 = eidx[i + 2], s3 = eidx[i + 3];
    int s4 = eidx[i + 4], s5 = eidx[i + 5], s6 = eidx[i + 6], s7 = eidx[i + 7];
    u32 v0 = hp[(size_t)s0 * 64 + lane];
    u32 v1 = hp[(size_t)s1 * 64 + lane];
    u32 v2 = hp[(size_t)s2 * 64 + lane];
    u32 v3 = hp[(size_t)s3 * 64 + lane];
    u32 v4 = hp[(size_t)s4 * 64 + lane];
    u32 v5 = hp[(size_t)s5 * 64 + lane];
    u32 v6 = hp[(size_t)s6 * 64 + lane];
    u32 v7 = hp[(size_t)s7 * 64 + lane];
    a = bmax(a, bmax(bmax(bmax(v0, v1), bmax(v2, v3)),
                     bmax(bmax(v4, v5), bmax(v6, v7))));
  }
  for (; i + 1 < e; i += 2) {
    u32 v0 = hp[(size_t)eidx[i] * 64 + lane];
    u32 v1 = hp[(size_t)eidx[i + 1] * 64 + lane];
    a = bmax(a, bmax(v0, v1));
  }
  if (i < e) a = bmax(a, hp[(size_t)eidx[i] * 64 + lane]);
  nb[(size_t)d * 64 + lane] = a;
}

// ---- BN stats ---------------------------------------------------------------
__global__ __launch_bounds__(256) void k_stats(
    const u16* __restrict__ xb, float* __restrict__ parts, int nchunks)
{
  __shared__ float sm[256][8];
  int t = threadIdx.x;
  float s[8], q[8];
#pragma unroll
  for (int j = 0; j < 8; j++) { s[j] = 0.f; q[j] = 0.f; }
  for (int i = blockIdx.x * 256 + t; i < nchunks; i += gridDim.x * 256) {
    uint4 v = ((const uint4*)xb)[i];
    float f;
    f = bf2f_lo(v.x); s[0] += f; q[0] += f * f;
    f = bf2f_hi(v.x); s[1] += f; q[1] += f * f;
    f = bf2f_lo(v.y); s[2] += f; q[2] += f * f;
    f = bf2f_hi(v.y); s[3] += f; q[3] += f * f;
    f = bf2f_lo(v.z); s[4] += f; q[4] += f * f;
    f = bf2f_hi(v.z); s[5] += f; q[5] += f * f;
    f = bf2f_lo(v.w); s[6] += f; q[6] += f * f;
    f = bf2f_hi(v.w); s[7] += f; q[7] += f * f;
  }
#pragma unroll
  for (int j = 0; j < 8; j++) sm[t][j] = s[j];
  __syncthreads();
  if (t < 128) {
    int fc = t >> 3, j = t & 7;
    float a = 0.f;
#pragma unroll
    for (int g = 0; g < 16; g++) a += sm[g * 16 + fc][j];
    parts[blockIdx.x * 256 + t] = a;
  }
  __syncthreads();
#pragma unroll
  for (int j = 0; j < 8; j++) sm[t][j] = q[j];
  __syncthreads();
  if (t < 128) {
    int fc = t >> 3, j = t & 7;
    float a = 0.f;
#pragma unroll
    for (int g = 0; g < 16; g++) a += sm[g * 16 + fc][j];
    parts[blockIdx.x * 256 + 128 + t] = a;
  }
}

__global__ __launch_bounds__(256) void k_bn_prep(
    const float* __restrict__ parts, int nb,
    const float* __restrict__ gamma, const float* __restrict__ beta,
    float* __restrict__ sc, float* __restrict__ sh, float invN)
{
  __shared__ float sums[256];
  int t = threadIdx.x;
  int c = t & 127, q = t >> 7;
  float s = 0.f;
  for (int b = 0; b < nb; b++) s += parts[b * 256 + q * 128 + c];
  sums[t] = s;
  __syncthreads();
  if (t < 128) {
    float mean = sums[t] * invN;
    float var = sums[128 + t] * invN - mean * mean;
    float g = gamma[t] * rsqrtf(var + 1e-5f);
    sc[t] = g;
    sh[t] = beta[t] - mean * g;
  }
}

__global__ __launch_bounds__(256) void k_bn_apply(
    const u16* __restrict__ xb, u16* __restrict__ hb, float* __restrict__ out,
    const float* __restrict__ sc, const float* __restrict__ sh, int n8, int last)
{
  int i = blockIdx.x * 256 + threadIdx.x;
  if (i >= n8) return;
  uint4 v = ((const uint4*)xb)[i];
  int f0 = (i & 15) * 8;
  float4 c0 = *(const float4*)(sc + f0);
  float4 c1 = *(const float4*)(sc + f0 + 4);
  float4 h0 = *(const float4*)(sh + f0);
  float4 h1 = *(const float4*)(sh + f0 + 4);
  float y0 = fmaxf(fmaf(bf2f_lo(v.x), c0.x, h0.x), 0.f);
  float y1 = fmaxf(fmaf(bf2f_hi(v.x), c0.y, h0.y), 0.f);
  float y2 = fmaxf(fmaf(bf2f_lo(v.y), c0.z, h0.z), 0.f);
  float y3 = fmaxf(fmaf(bf2f_hi(v.y), c0.w, h0.w), 0.f);
  float y4 = fmaxf(fmaf(bf2f_lo(v.z), c1.x, h1.x), 0.f);
  float y5 = fmaxf(fmaf(bf2f_hi(v.z), c1.y, h1.y), 0.f);
  float y6 = fmaxf(fmaf(bf2f_lo(v.w), c1.z, h1.z), 0.f);
  float y7 = fmaxf(fmaf(bf2f_hi(v.w), c1.w, h1.w), 0.f);
  if (last) {
    float4* o = (float4*)out + 2 * (size_t)i;
    o[0] = make_float4(y0, y1, y2, y3);
    o[1] = make_float4(y4, y5, y6, y7);
  } else {
    uint4 o;
    o.x = (u32)f2bf(y0) | ((u32)f2bf(y1) << 16);
    o.y = (u32)f2bf(y2) | ((u32)f2bf(y3) << 16);
    o.z = (u32)f2bf(y4) | ((u32)f2bf(y5) << 16);
    o.w = (u32)f2bf(y6) | ((u32)f2bf(y7) << 16);
    ((uint4*)hb)[i] = o;
  }
}

// ---- launcher ---------------------------------------------------------------
extern "C" void kernel_launch(void* const* d_in, const int* in_sizes, int n_in,
                              void* d_out, int out_size, void* d_ws, size_t ws_size,
                              hipStream_t stream)
{
  const float* feat    = (const float*)d_in[0];
  const float* W_pool  = (const float*)d_in[1];
  const float* b_pool  = (const float*)d_in[2];
  const float* W_self  = (const float*)d_in[3];
  const float* W_neigh = (const float*)d_in[4];
  const float* bias    = (const float*)d_in[5];
  const float* gamma   = (const float*)d_in[6];
  const float* beta    = (const float*)d_in[7];
  const int*   src     = (const int*)d_in[8];
  const int*   dst     = (const int*)d_in[9];

  const int Nn = in_sizes[0] / DD;   // 100000
  const int E  = in_sizes[8];        // 1600000
  float* out = (float*)d_out;

  const size_t ND = (size_t)Nn * DD;
  u16*   hb    = (u16*)d_ws;                    // ND bf16
  u16*   hp    = hb + ND;                       // ND bf16 (also xb)
  u16*   nbuf  = hp + ND;                       // ND bf16
  u16*   Wpk   = nbuf + ND;                     // 9*16384 bf16
  float* parts = (float*)(Wpk + 9 * 16384);     // SB*256 f32
  float* sc    = parts + SB * 256;              // 128
  float* sh    = sc + DD;                       // 128
  int*   off   = (int*)(sh + DD);               // Nn+2 (even pad)
  int*   bcnt  = off + Nn + 2;                  // MAXB
  int*   boff  = bcnt + MAXB;                   // MAXB+2
  int*   bcur  = boff + MAXB + 2;               // MAXB
  int2*  pairs = (int2*)(bcur + MAXB);          // E (8B aligned)
  int*   eidx  = (int*)(pairs + E);             // E

  const int nbuk = (Nn + 511) >> BSH;           // 196
  const int gB   = (Nn + 127) / 128;
  const int pB   = (E + PEB - 1) / PEB;         // 391
  const int aggB = (Nn + 3) / 4;
  const int n8   = Nn * (DD / 8);
  const int cB   = (n8 + 255) / 256;

  // one-time setup
  k_pack_w<<<72, 256, 0, stream>>>(W_pool, W_self, W_neigh, Wpk);
  k_cast<<<cB, 256, 0, stream>>>(feat, hb, n8);
  k_zero_i<<<1, 256, 0, stream>>>(bcnt, MAXB);
  k_histb<<<pB, 256, 0, stream>>>(dst, bcnt, E);
  k_bscan<<<1, 256, 0, stream>>>(bcnt, boff, bcur, nbuk, E);
  k_part<<<pB, 256, 0, stream>>>(src, dst, bcur, pairs, E);
  k_csr<<<nbuk, 256, 0, stream>>>(pairs, boff, off, eidx, Nn, nbuk);

  for (int l = 0; l < 3; l++) {
    const float* bp = b_pool + (size_t)l * DD;
    const float* bl = bias + (size_t)l * DD;
    k_gemm_pool<<<gB, 256, 0, stream>>>(hb, Wpk + (size_t)l * 16384, bp, hp, Nn);
    k_aggregate<<<aggB, 256, 0, stream>>>((const u32*)hp, off, eidx, (u32*)nbuf, Nn);
    k_gemm_out<<<gB, 256, 0, stream>>>(hb, nbuf, Wpk + (size_t)(3 + l) * 16384,
                                       Wpk + (size_t)(6 + l) * 16384, bl, hp, Nn);
    k_stats<<<SB, 256, 0, stream>>>(hp, parts, Nn * 16);
    k_bn_prep<<<1, 256, 0, stream>>>(parts, SB, gamma + (size_t)l * DD,
                                     beta + (size_t)l * DD, sc, sh, 1.0f / (float)Nn);
    k_bn_apply<<<cB, 256, 0, stream>>>(hp, hb, out, sc, sh, n8, l == 2);
  }
  (void)n_in; (void)out_size; (void)ws_size;
}

// Round 7
// 499.409 us; speedup vs baseline: 4.1416x; 1.2057x over previous
//
#include <hip/hip_runtime.h>

#define DD 128
#define MAXB 256  // max dst-buckets (supports N <= 131072)
#define BSH 9     // bucket = dst >> 9  (512 nodes/bucket)
#define PEB 4096  // edges per partition block

typedef unsigned short u16;
typedef unsigned int   u32;
typedef __attribute__((ext_vector_type(8))) short bf16x8;
typedef __attribute__((ext_vector_type(4))) float f32x4;

union U8 { uint4 u; bf16x8 v; };

__device__ inline u16 f2bf(float x) {
  u32 u = __float_as_uint(x);
  u += 0x7fffu + ((u >> 16) & 1u);
  return (u16)(u >> 16);
}
__device__ inline float bf2f_lo(u32 w) { return __uint_as_float(w << 16); }
__device__ inline float bf2f_hi(u32 w) { return __uint_as_float(w & 0xffff0000u); }
__device__ inline u32 bmax(u32 a, u32 b) {
  u32 al = a & 0xffffu, bl = b & 0xffffu;
  u32 ah = a >> 16,     bh = b >> 16;
  u32 lo = al > bl ? al : bl;
  u32 hi = ah > bh ? ah : bh;
  return lo | (hi << 16);
}

// frag loaders: produce a bf16x8 MFMA B-fragment (8 consecutive k-elems)
__device__ inline uint4 fragF32(const float* __restrict__ p) {
  float4 a = *(const float4*)p;
  float4 b = *(const float4*)(p + 4);
  uint4 o;
  o.x = (u32)f2bf(a.x) | ((u32)f2bf(a.y) << 16);
  o.y = (u32)f2bf(a.z) | ((u32)f2bf(a.w) << 16);
  o.z = (u32)f2bf(b.x) | ((u32)f2bf(b.y) << 16);
  o.w = (u32)f2bf(b.z) | ((u32)f2bf(b.w) << 16);
  return o;
}

__device__ inline uint4 fragBN(const u16* __restrict__ p,
                               const float* __restrict__ sc,
                               const float* __restrict__ sh, int k0) {
  uint4 u = *(const uint4*)p;
  float4 c0 = *(const float4*)(sc + k0);
  float4 c1 = *(const float4*)(sc + k0 + 4);
  float4 h0 = *(const float4*)(sh + k0);
  float4 h1 = *(const float4*)(sh + k0 + 4);
  float y0 = fmaxf(fmaf(bf2f_lo(u.x), c0.x, h0.x), 0.f);
  float y1 = fmaxf(fmaf(bf2f_hi(u.x), c0.y, h0.y), 0.f);
  float y2 = fmaxf(fmaf(bf2f_lo(u.y), c0.z, h0.z), 0.f);
  float y3 = fmaxf(fmaf(bf2f_hi(u.y), c0.w, h0.w), 0.f);
  float y4 = fmaxf(fmaf(bf2f_lo(u.z), c1.x, h1.x), 0.f);
  float y5 = fmaxf(fmaf(bf2f_hi(u.z), c1.y, h1.y), 0.f);
  float y6 = fmaxf(fmaf(bf2f_lo(u.w), c1.z, h1.z), 0.f);
  float y7 = fmaxf(fmaf(bf2f_hi(u.w), c1.w, h1.w), 0.f);
  uint4 o;
  o.x = (u32)f2bf(y0) | ((u32)f2bf(y1) << 16);
  o.y = (u32)f2bf(y2) | ((u32)f2bf(y3) << 16);
  o.z = (u32)f2bf(y4) | ((u32)f2bf(y5) << 16);
  o.w = (u32)f2bf(y6) | ((u32)f2bf(y7) << 16);
  return o;
}

// ---- pack 9 weight matrices (fp32 [k][n]) into MFMA A-frag layout, bf16 ----
__global__ __launch_bounds__(256) void k_pack_w(
    const float* __restrict__ Wp, const float* __restrict__ Wsf,
    const float* __restrict__ Wn, u16* __restrict__ Wpk)
{
  int g = blockIdx.x * 256 + threadIdx.x;      // 9 * 2048
  int m = g >> 11;
  if (m >= 9) return;
  int t = g & 2047;
  const float* W = (m < 3) ? Wp + (size_t)m * 16384
                 : (m < 6) ? Wsf + (size_t)(m - 3) * 16384
                           : Wn + (size_t)(m - 6) * 16384;
  int ks = t >> 9, nt = (t >> 6) & 7, l = t & 63;
  int kbase = ks * 32 + (l >> 4) * 8;
  int n = nt * 16 + (l & 15);
  u32 o[4];
#pragma unroll
  for (int p = 0; p < 4; p++) {
    u16 e0 = f2bf(W[(size_t)(kbase + 2 * p) * DD + n]);
    u16 e1 = f2bf(W[(size_t)(kbase + 2 * p + 1) * DD + n]);
    o[p] = (u32)e0 | ((u32)e1 << 16);
  }
  uint4* dst = (uint4*)(Wpk + (size_t)m * 16384 + (size_t)t * 8);
  *dst = make_uint4(o[0], o[1], o[2], o[3]);
}

// ---- GEMM 1: hp = relu(h_in @ W + b); MODE 0: h_in = feat fp32 (cast inline)
//              MODE 1: h_in = BN_relu(xb) inline (sc/sh from prev layer) ------
template<int MODE>
__global__ __launch_bounds__(256, 2) void k_gemm_pool(
    const float* __restrict__ featf, const u16* __restrict__ xb,
    const u16* __restrict__ Wpk, const float* __restrict__ bvec,
    const float* __restrict__ sc, const float* __restrict__ sh,
    u16* __restrict__ hp, int nrows)
{
  const int tid = threadIdx.x;
  const int w = tid >> 6, l = tid & 63;
  const int lg = l >> 4, lm = l & 15;
  const int m0 = blockIdx.x * 128 + w * 32;

  f32x4 acc[2][8];
#pragma unroll
  for (int a = 0; a < 2; a++)
#pragma unroll
    for (int b = 0; b < 8; b++) acc[a][b] = (f32x4){0.f, 0.f, 0.f, 0.f};

  int n0 = m0 + lm;      if (n0 >= nrows) n0 = nrows - 1;
  int n1 = m0 + 16 + lm; if (n1 >= nrows) n1 = nrows - 1;
  const u16* wl = Wpk + l * 8;

#pragma unroll
  for (int ks = 0; ks < 4; ks++) {
    const int k0 = ks * 32 + lg * 8;
    U8 a0, a1;
    if (MODE == 0) {
      a0.u = fragF32(featf + (size_t)n0 * DD + k0);
      a1.u = fragF32(featf + (size_t)n1 * DD + k0);
    } else {
      a0.u = fragBN(xb + (size_t)n0 * DD + k0, sc, sh, k0);
      a1.u = fragBN(xb + (size_t)n1 * DD + k0, sc, sh, k0);
    }
#pragma unroll
    for (int nt = 0; nt < 8; nt++) {
      bf16x8 wf = *(const bf16x8*)(wl + (ks * 8 + nt) * 512);
      acc[0][nt] = __builtin_amdgcn_mfma_f32_16x16x32_bf16(wf, a0.v, acc[0][nt], 0, 0, 0);
      acc[1][nt] = __builtin_amdgcn_mfma_f32_16x16x32_bf16(wf, a1.v, acc[1][nt], 0, 0, 0);
    }
  }

#pragma unroll
  for (int mf = 0; mf < 2; mf++) {
    int node = m0 + mf * 16 + lm;
    if (node < nrows) {
      u16* dst = hp + (size_t)node * DD + lg * 4;
#pragma unroll
      for (int nt = 0; nt < 8; nt++) {
        float4 b4 = *(const float4*)(bvec + nt * 16 + lg * 4);
        f32x4 a = acc[mf][nt];
        float v0 = fmaxf(a[0] + b4.x, 0.f);
        float v1 = fmaxf(a[1] + b4.y, 0.f);
        float v2 = fmaxf(a[2] + b4.z, 0.f);
        float v3 = fmaxf(a[3] + b4.w, 0.f);
        uint2 o;
        o.x = (u32)f2bf(v0) | ((u32)f2bf(v1) << 16);
        o.y = (u32)f2bf(v2) | ((u32)f2bf(v3) << 16);
        *(uint2*)(dst + nt * 16) = o;
      }
    }
  }
}

// ---- GEMM 2: xb_out = h_in@Ws + nbuf@Wn + b, in-place on xb, + BN stats ----
// In-place safe: each block reads only its own 128 rows (self + nbuf), all
// reads complete before epilogue stores. MODE as in k_gemm_pool.
template<int MODE>
__global__ __launch_bounds__(256, 2) void k_gemm_out(
    const float* __restrict__ featf, u16* xb,
    const u16* __restrict__ gb,
    const u16* __restrict__ WpkS, const u16* __restrict__ WpkN,
    const float* __restrict__ bvec,
    const float* __restrict__ sc, const float* __restrict__ sh,
    float* __restrict__ stats, int nrows)
{
  __shared__ float st[256];
  const int tid = threadIdx.x;
  const int w = tid >> 6, l = tid & 63;
  const int lg = l >> 4, lm = l & 15;
  const int m0 = blockIdx.x * 128 + w * 32;
  st[tid] = 0.f;

  f32x4 acc[2][8];
#pragma unroll
  for (int a = 0; a < 2; a++)
#pragma unroll
    for (int b = 0; b < 8; b++) acc[a][b] = (f32x4){0.f, 0.f, 0.f, 0.f};

  int n0 = m0 + lm;      if (n0 >= nrows) n0 = nrows - 1;
  int n1 = m0 + 16 + lm; if (n1 >= nrows) n1 = nrows - 1;

  // pass 0: self operand (BN/cast inline)
#pragma unroll
  for (int ks = 0; ks < 4; ks++) {
    const int k0 = ks * 32 + lg * 8;
    U8 a0, a1;
    if (MODE == 0) {
      a0.u = fragF32(featf + (size_t)n0 * DD + k0);
      a1.u = fragF32(featf + (size_t)n1 * DD + k0);
    } else {
      a0.u = fragBN(xb + (size_t)n0 * DD + k0, sc, sh, k0);
      a1.u = fragBN(xb + (size_t)n1 * DD + k0, sc, sh, k0);
    }
    const u16* wl = WpkS + l * 8;
#pragma unroll
    for (int nt = 0; nt < 8; nt++) {
      bf16x8 wf = *(const bf16x8*)(wl + (ks * 8 + nt) * 512);
      acc[0][nt] = __builtin_amdgcn_mfma_f32_16x16x32_bf16(wf, a0.v, acc[0][nt], 0, 0, 0);
      acc[1][nt] = __builtin_amdgcn_mfma_f32_16x16x32_bf16(wf, a1.v, acc[1][nt], 0, 0, 0);
    }
  }
  // pass 1: neigh operand (plain bf16)
#pragma unroll
  for (int ks = 0; ks < 4; ks++) {
    const int k0 = ks * 32 + lg * 8;
    bf16x8 g0 = *(const bf16x8*)(gb + (size_t)n0 * DD + k0);
    bf16x8 g1 = *(const bf16x8*)(gb + (size_t)n1 * DD + k0);
    const u16* wl = WpkN + l * 8;
#pragma unroll
    for (int nt = 0; nt < 8; nt++) {
      bf16x8 wf = *(const bf16x8*)(wl + (ks * 8 + nt) * 512);
      acc[0][nt] = __builtin_amdgcn_mfma_f32_16x16x32_bf16(wf, g0, acc[0][nt], 0, 0, 0);
      acc[1][nt] = __builtin_amdgcn_mfma_f32_16x16x32_bf16(wf, g1, acc[1][nt], 0, 0, 0);
    }
  }

  __syncthreads();  // st zeroed by all threads at kernel start

  // bias + stats (fp32, pre-rounding); shfl-reduce over the 16 node lanes
  float msk0 = (m0 + lm < nrows) ? 1.f : 0.f;
  float msk1 = (m0 + 16 + lm < nrows) ? 1.f : 0.f;
#pragma unroll
  for (int nt = 0; nt < 8; nt++) {
    float4 b4 = *(const float4*)(bvec + nt * 16 + lg * 4);
    float bj[4] = {b4.x, b4.y, b4.z, b4.w};
    float s[4], q[4];
#pragma unroll
    for (int j = 0; j < 4; j++) {
      float v0 = acc[0][nt][j] + bj[j];
      float v1 = acc[1][nt][j] + bj[j];
      acc[0][nt][j] = v0; acc[1][nt][j] = v1;
      s[j] = msk0 * v0 + msk1 * v1;
      q[j] = msk0 * v0 * v0 + msk1 * v1 * v1;
    }
#pragma unroll
    for (int m = 1; m < 16; m <<= 1) {
#pragma unroll
      for (int j = 0; j < 4; j++) {
        s[j] += __shfl_xor(s[j], m, 64);
        q[j] += __shfl_xor(q[j], m, 64);
      }
    }
    if (lm == 0) {
#pragma unroll
      for (int j = 0; j < 4; j++) {
        atomicAdd(&st[nt * 16 + lg * 4 + j], s[j]);
        atomicAdd(&st[128 + nt * 16 + lg * 4 + j], q[j]);
      }
    }
  }

  // store xb in place
#pragma unroll
  for (int mf = 0; mf < 2; mf++) {
    int node = m0 + mf * 16 + lm;
    if (node < nrows) {
      u16* dst = xb + (size_t)node * DD + lg * 4;
#pragma unroll
      for (int nt = 0; nt < 8; nt++) {
        f32x4 a = acc[mf][nt];
        uint2 o;
        o.x = (u32)f2bf(a[0]) | ((u32)f2bf(a[1]) << 16);
        o.y = (u32)f2bf(a[2]) | ((u32)f2bf(a[3]) << 16);
        *(uint2*)(dst + nt * 16) = o;
      }
    }
  }
  __syncthreads();
  atomicAdd(&stats[tid], st[tid]);
}

// ---- CSR build --------------------------------------------------------------
__global__ __launch_bounds__(256) void k_zero_i(int* p, int n) {
  int i = blockIdx.x * 256 + threadIdx.x;
  if (i < n) p[i] = 0;
}

__global__ __launch_bounds__(256) void k_histb(
    const int* __restrict__ dst, int* __restrict__ bcnt, int E)
{
  __shared__ int cnt[MAXB];
  const int e0 = blockIdx.x * PEB;
  const int e1 = min(e0 + PEB, E);
  for (int i = threadIdx.x; i < MAXB; i += 256) cnt[i] = 0;
  __syncthreads();
  for (int e = e0 + threadIdx.x; e < e1; e += 256)
    atomicAdd(&cnt[dst[e] >> BSH], 1);
  __syncthreads();
  for (int i = threadIdx.x; i < MAXB; i += 256)
    if (cnt[i]) atomicAdd(&bcnt[i], cnt[i]);
}

__global__ __launch_bounds__(256) void k_bscan(
    const int* __restrict__ bcnt, int* __restrict__ boff,
    int* __restrict__ bcur, int nbuk, int E)
{
  __shared__ int sm[256];
  int t = threadIdx.x;
  int v = (t < nbuk) ? bcnt[t] : 0;
  sm[t] = v;
  __syncthreads();
  int acc = v;
#pragma unroll
  for (int s = 1; s < 256; s <<= 1) {
    int u = (t >= s) ? sm[t - s] : 0;
    __syncthreads();
    acc += u;
    sm[t] = acc;
    __syncthreads();
  }
  if (t < nbuk) { boff[t] = acc - v; bcur[t] = acc - v; }
  if (t == 0) boff[nbuk] = E;
}

__global__ __launch_bounds__(256) void k_part(
    const int* __restrict__ src, const int* __restrict__ dst,
    int* __restrict__ bcur, int2* __restrict__ pairs, int E)
{
  __shared__ int cnt[MAXB];
  __shared__ int base[MAXB];
  const int e0 = blockIdx.x * PEB;
  const int e1 = min(e0 + PEB, E);
  for (int i = threadIdx.x; i < MAXB; i += 256) cnt[i] = 0;
  __syncthreads();
  for (int e = e0 + threadIdx.x; e < e1; e += 256)
    atomicAdd(&cnt[dst[e] >> BSH], 1);
  __syncthreads();
  for (int i = threadIdx.x; i < MAXB; i += 256) {
    int c = cnt[i];
    base[i] = c ? atomicAdd(&bcur[i], c) : 0;
    cnt[i] = 0;
  }
  __syncthreads();
  for (int e = e0 + threadIdx.x; e < e1; e += 256) {
    int d = dst[e], s = src[e];
    int b = d >> BSH;
    int r = atomicAdd(&cnt[b], 1);
    pairs[base[b] + r] = make_int2(s, d);
  }
}

__global__ __launch_bounds__(256) void k_csr(
    const int2* __restrict__ pairs, const int* __restrict__ boff,
    int* __restrict__ off, int* __restrict__ eidx, int nrows, int nbuk)
{
  __shared__ int cnt[512];
  __shared__ int ps[256];
  const int b = blockIdx.x;
  const int lo = boff[b], hi = boff[b + 1];
  const int t = threadIdx.x;
  cnt[t] = 0; cnt[t + 256] = 0;
  __syncthreads();
  for (int i = lo + t; i < hi; i += 256)
    atomicAdd(&cnt[pairs[i].y & 511], 1);
  __syncthreads();
  int c0 = cnt[2 * t], c1 = cnt[2 * t + 1];
  ps[t] = c0 + c1;
  __syncthreads();
  int acc = ps[t];
#pragma unroll
  for (int s = 1; s < 256; s <<= 1) {
    int u = (t >= s) ? ps[t - s] : 0;
    __syncthreads();
    acc += u;
    ps[t] = acc;
    __syncthreads();
  }
  int base = lo + acc - (c0 + c1);
  int node0 = (b << BSH) + 2 * t;
  if (node0 < nrows)     off[node0]     = base;
  if (node0 + 1 < nrows) off[node0 + 1] = base + c0;
  if (b == nbuk - 1 && t == 0) off[nrows] = hi;
  cnt[2 * t]     = base;
  cnt[2 * t + 1] = base + c0;
  __syncthreads();
  for (int i = lo + t; i < hi; i += 256) {
    int2 p = pairs[i];
    int pos = atomicAdd(&cnt[p.y & 511], 1);
    eidx[pos] = p.x;
  }
}

// ---- aggregate: neigh[d] = max(hp[d], max over in-edges), bf16, 8-deep -----
__global__ __launch_bounds__(256) void k_aggregate(
    const u32* __restrict__ hp, const int* __restrict__ off,
    const int* __restrict__ eidx, u32* __restrict__ nb, int nrows)
{
  int d = blockIdx.x * 4 + (threadIdx.x >> 6);
  if (d >= nrows) return;
  int lane = threadIdx.x & 63;
  u32 a = hp[(size_t)d * 64 + lane];
  int b = off[d], e = off[d + 1];
  int i = b;
  for (; i + 7 < e; i += 8) {
    int s0 = eidx[i],     s1 = eidx[i + 1], s2 = eidx[i + 2], s3 = eidx[i + 3];
    int s4 = eidx[i + 4], s5 = eidx[i + 5], s6 = eidx[i + 6], s7 = eidx[i + 7];
    u32 v0 = hp[(size_t)s0 * 64 + lane];
    u32 v1 = hp[(size_t)s1 * 64 + lane];
    u32 v2 = hp[(size_t)s2 * 64 + lane];
    u32 v3 = hp[(size_t)s3 * 64 + lane];
    u32 v4 = hp[(size_t)s4 * 64 + lane];
    u32 v5 = hp[(size_t)s5 * 64 + lane];
    u32 v6 = hp[(size_t)s6 * 64 + lane];
    u32 v7 = hp[(size_t)s7 * 64 + lane];
    a = bmax(a, bmax(bmax(bmax(v0, v1), bmax(v2, v3)),
                     bmax(bmax(v4, v5), bmax(v6, v7))));
  }
  for (; i + 1 < e; i += 2) {
    u32 v0 = hp[(size_t)eidx[i] * 64 + lane];
    u32 v1 = hp[(size_t)eidx[i + 1] * 64 + lane];
    a = bmax(a, bmax(v0, v1));
  }
  if (i < e) a = bmax(a, hp[(size_t)eidx[i] * 64 + lane]);
  nb[(size_t)d * 64 + lane] = a;
}

// ---- BN prep: stats slot -> sc/sh -------------------------------------------
__global__ void k_bn_prep(const float* __restrict__ stats,
                          const float* __restrict__ gamma,
                          const float* __restrict__ beta,
                          float* __restrict__ sc, float* __restrict__ sh,
                          float invN)
{
  int t = threadIdx.x;  // 128
  float mean = stats[t] * invN;
  float var  = stats[128 + t] * invN - mean * mean;
  float g = gamma[t] * rsqrtf(var + 1e-5f);
  sc[t] = g;
  sh[t] = beta[t] - mean * g;
}

// ---- final BN+relu -> fp32 out ----------------------------------------------
__global__ __launch_bounds__(256) void k_bn_final(
    const u16* __restrict__ xb, float* __restrict__ out,
    const float* __restrict__ sc, const float* __restrict__ sh, int n8)
{
  int i = blockIdx.x * 256 + threadIdx.x;
  if (i >= n8) return;
  uint4 v = ((const uint4*)xb)[i];
  int f0 = (i & 15) * 8;
  float4 c0 = *(const float4*)(sc + f0);
  float4 c1 = *(const float4*)(sc + f0 + 4);
  float4 h0 = *(const float4*)(sh + f0);
  float4 h1 = *(const float4*)(sh + f0 + 4);
  float4* o = (float4*)out + 2 * (size_t)i;
  o[0] = make_float4(fmaxf(fmaf(bf2f_lo(v.x), c0.x, h0.x), 0.f),
                     fmaxf(fmaf(bf2f_hi(v.x), c0.y, h0.y), 0.f),
                     fmaxf(fmaf(bf2f_lo(v.y), c0.z, h0.z), 0.f),
                     fmaxf(fmaf(bf2f_hi(v.y), c0.w, h0.w), 0.f));
  o[1] = make_float4(fmaxf(fmaf(bf2f_lo(v.z), c1.x, h1.x), 0.f),
                     fmaxf(fmaf(bf2f_hi(v.z), c1.y, h1.y), 0.f),
                     fmaxf(fmaf(bf2f_lo(v.w), c1.z, h1.z), 0.f),
                     fmaxf(fmaf(bf2f_hi(v.w), c1.w, h1.w), 0.f));
}

// ---- launcher ---------------------------------------------------------------
extern "C" void kernel_launch(void* const* d_in, const int* in_sizes, int n_in,
                              void* d_out, int out_size, void* d_ws, size_t ws_size,
                              hipStream_t stream)
{
  const float* feat    = (const float*)d_in[0];
  const float* W_pool  = (const float*)d_in[1];
  const float* b_pool  = (const float*)d_in[2];
  const float* W_self  = (const float*)d_in[3];
  const float* W_neigh = (const float*)d_in[4];
  const float* bias    = (const float*)d_in[5];
  const float* gamma   = (const float*)d_in[6];
  const float* beta    = (const float*)d_in[7];
  const int*   src     = (const int*)d_in[8];
  const int*   dst     = (const int*)d_in[9];

  const int Nn = in_sizes[0] / DD;   // 100000
  const int E  = in_sizes[8];        // 1600000
  float* out = (float*)d_out;

  const size_t ND = (size_t)Nn * DD;
  u16*   xb    = (u16*)d_ws;                    // ND bf16 (x, in-place per layer)
  u16*   hp    = xb + ND;                       // ND bf16
  u16*   nbuf  = hp + ND;                       // ND bf16
  u16*   Wpk   = nbuf + ND;                     // 9*16384 bf16
  float* sc    = (float*)(Wpk + 9 * 16384);     // 128
  float* sh    = sc + 128;                      // 128
  int*   bcnt  = (int*)(sh + 128);              // MAXB   (zeroed with stats)
  float* stats = (float*)(bcnt + MAXB);         // 768 = 3 layer slots
  int*   off   = (int*)(stats + 768);           // Nn+2
  int*   boff  = off + Nn + 2;                  // MAXB+2
  int*   bcur  = boff + MAXB + 2;               // MAXB
  int2*  pairs = (int2*)(bcur + MAXB);          // E
  int*   eidx  = (int*)(pairs + E);             // E

  const int nbuk = (Nn + 511) >> BSH;           // 196
  const int gB   = (Nn + 127) / 128;            // 782
  const int pB   = (E + PEB - 1) / PEB;         // 391
  const int aggB = (Nn + 3) / 4;
  const int n8   = Nn * (DD / 8);
  const int cB   = (n8 + 255) / 256;

  // one-time setup
  k_pack_w<<<72, 256, 0, stream>>>(W_pool, W_self, W_neigh, Wpk);
  k_zero_i<<<4, 256, 0, stream>>>(bcnt, MAXB + 768);   // bcnt + 3 stats slots
  k_histb<<<pB, 256, 0, stream>>>(dst, bcnt, E);
  k_bscan<<<1, 256, 0, stream>>>(bcnt, boff, bcur, nbuk, E);
  k_part<<<pB, 256, 0, stream>>>(src, dst, bcur, pairs, E);
  k_csr<<<nbuk, 256, 0, stream>>>(pairs, boff, off, eidx, Nn, nbuk);

  for (int l = 0; l < 3; l++) {
    const float* bp = b_pool + (size_t)l * DD;
    const float* bl = bias + (size_t)l * DD;
    const u16* WP = Wpk + (size_t)l * 16384;
    const u16* WS = Wpk + (size_t)(3 + l) * 16384;
    const u16* WN = Wpk + (size_t)(6 + l) * 16384;
    float* stl = stats + l * 256;

    if (l == 0)
      k_gemm_pool<0><<<gB, 256, 0, stream>>>(feat, nullptr, WP, bp, sc, sh, hp, Nn);
    else
      k_gemm_pool<1><<<gB, 256, 0, stream>>>(nullptr, xb, WP, bp, sc, sh, hp, Nn);

    k_aggregate<<<aggB, 256, 0, stream>>>((const u32*)hp, off, eidx, (u32*)nbuf, Nn);

    if (l == 0)
      k_gemm_out<0><<<gB, 256, 0, stream>>>(feat, xb, nbuf, WS, WN, bl, sc, sh, stl, Nn);
    else
      k_gemm_out<1><<<gB, 256, 0, stream>>>(nullptr, xb, nbuf, WS, WN, bl, sc, sh, stl, Nn);

    k_bn_prep<<<1, 128, 0, stream>>>(stl, gamma + (size_t)l * DD,
                                     beta + (size_t)l * DD, sc, sh, 1.0f / (float)Nn);
  }
  k_bn_final<<<cB, 256, 0, stream>>>(xb, out, sc, sh, n8);
  (void)n_in; (void)out_size; (void)ws_size;
}